// Round 1
// baseline (25646.252 us; speedup 1.0000x reference)
//
#include <hip/hip_runtime.h>
#include <hip/hip_cooperative_groups.h>

namespace cg = cooperative_groups;

#define RFL(x) __builtin_amdgcn_readfirstlane(x)

__device__ __forceinline__ float sigm(float x) { return 1.0f / (1.0f + __expf(-x)); }

// ---------------- K0: transpose inputs (B,S,512) -> XT4[s][k/4][b][4] ----------------
__global__ void __launch_bounds__(256) k0_transpose(const float* __restrict__ in, float* __restrict__ XT4) {
  __shared__ float lds[32 * 260];
  int blk = blockIdx.x;            // s(512) * kh(2) * bh(2)
  int s  = blk >> 2;
  int kh = (blk >> 1) & 1;
  int bh = blk & 1;
  int t = threadIdx.x;
  const float4* in4 = (const float4*)in;
  for (int pass = 0; pass < 8; ++pass) {
    int q = pass * 256 + t;        // f4 over [32 b][64 k4]
    int bl = q >> 6, k4 = q & 63;
    float4 v = in4[ ((size_t)((bh * 32 + bl) * 512 + s)) * 128 + kh * 64 + k4 ];
    *(float4*)&lds[bl * 260 + k4 * 4] = v;
  }
  __syncthreads();
  float4* out4 = (float4*)XT4;
  for (int pass = 0; pass < 8; ++pass) {
    int q = pass * 256 + t;        // f4 over [64 g4][32 b]
    int g4 = q >> 5, bl = q & 31;
    float4 v = *(const float4*)&lds[bl * 260 + g4 * 4];
    out4[ ((size_t)s * 128 + kh * 64 + g4) * 64 + bh * 32 + bl ] = v;
  }
}

// ---------------- K1: xg chunk producer. XG[d][tl][2048 rows][64 b] ----------------
// grid 1024: wg = d(1b) | gs(7b) | s8(2b); 4 waves = 4 step-pairs; lane = b
__global__ void __launch_bounds__(256) k1_xg(const float* __restrict__ XT4,
    const float* __restrict__ Wih_f, const float* __restrict__ Wih_b,
    const float* __restrict__ bih_f, const float* __restrict__ bhh_f,
    const float* __restrict__ bih_b, const float* __restrict__ bhh_b,
    float* __restrict__ XG, int c0) {
  int wg = blockIdx.x;
  int d  = wg & 1;
  int gs = (wg >> 1) & 127;
  int s8 = wg >> 8;                         // [0,4)
  int wid = RFL((int)(threadIdx.x >> 6));
  int b = threadIdx.x & 63;
  int tl0 = s8 * 8 + wid * 2;
  int t0 = c0 + tl0;
  int pos0 = d ? (511 - t0) : t0;
  int pos1 = d ? (511 - (t0 + 1)) : (t0 + 1);
  const float* Wih = d ? Wih_b : Wih_f;
  const float* bih = d ? bih_b : bih_f;
  const float* bhh = d ? bhh_b : bhh_f;
  const float* __restrict__ W0 = Wih + (size_t)gs * 16 * 512;
  float acc0[16], acc1[16];
#pragma unroll
  for (int r = 0; r < 16; ++r) {
    float bb = bih[gs * 16 + r] + bhh[gs * 16 + r];
    acc0[r] = bb; acc1[r] = bb;
  }
  const float4* X4 = (const float4*)XT4;
  for (int kc = 0; kc < 512; kc += 4) {
    float4 x0 = X4[((size_t)pos0 * 128 + (kc >> 2)) * 64 + b];
    float4 x1 = X4[((size_t)pos1 * 128 + (kc >> 2)) * 64 + b];
#pragma unroll
    for (int r = 0; r < 16; ++r) {
      float4 wv = *(const float4*)&W0[(size_t)r * 512 + kc];
      acc0[r] = fmaf(wv.x, x0.x, acc0[r]); acc0[r] = fmaf(wv.y, x0.y, acc0[r]);
      acc0[r] = fmaf(wv.z, x0.z, acc0[r]); acc0[r] = fmaf(wv.w, x0.w, acc0[r]);
      acc1[r] = fmaf(wv.x, x1.x, acc1[r]); acc1[r] = fmaf(wv.y, x1.y, acc1[r]);
      acc1[r] = fmaf(wv.z, x1.z, acc1[r]); acc1[r] = fmaf(wv.w, x1.w, acc1[r]);
    }
  }
#pragma unroll
  for (int r = 0; r < 16; ++r) {
    XG[((size_t)(d * 32 + tl0)     * 2048 + gs * 16 + r) * 64 + b] = acc0[r];
    XG[((size_t)(d * 32 + tl0 + 1) * 2048 + gs * 16 + r) * 64 + b] = acc1[r];
  }
}

// ---------------- K2: cooperative recurrence, 32 steps per launch ----------------
// grid 256: wg = (d = w&1, m = w>>1); 4 waves = hidden j in {4m..4m+3}; lane = b
// LDS: h[64][512] fp32, float4-group XOR-swizzled by (b&7); + 64x5 transpose tile
__global__ void __launch_bounds__(256, 1) k2_rnn(const float* __restrict__ Whh_f,
    const float* __restrict__ Whh_b, const float* __restrict__ XG,
    float* __restrict__ HT, float* __restrict__ OUTT, float* __restrict__ Cws, int t0) {
  extern __shared__ float lds[];
  float4* lds4 = (float4*)lds;
  cg::grid_group grid = cg::this_grid();
  int w = blockIdx.x;
  int d = w & 1, m = w >> 1;
  int tid = threadIdx.x;
  int wid = RFL((int)(tid >> 6));
  int b = tid & 63;
  int j = m * 4 + wid;
  const float* Whh = d ? Whh_b : Whh_f;
  const float* __restrict__ wr0 = Whh + (size_t)(0   + j) * 512;
  const float* __restrict__ wr1 = Whh + (size_t)(512 + j) * 512;
  const float* __restrict__ wr2 = Whh + (size_t)(1024 + j) * 512;
  const float* __restrict__ wr3 = Whh + (size_t)(1536 + j) * 512;
  float c = Cws[(size_t)(d * 512 + j) * 64 + b];
  int bsw = b & 7, bbase = b * 128;
  for (int tl = 0; tl < 32; ++tl) {
    int t = t0 + tl, p = t & 1;
    const float4* src = (const float4*)(HT + (size_t)(p * 2 + d) * 32768);
#pragma unroll 8
    for (int i = 0; i < 32; ++i) {
      int q = i * 256 + tid, bb = q >> 7, g = q & 127;
      lds4[bb * 128 + (g ^ (bb & 7))] = src[q];
    }
    __syncthreads();
    float a0 = 0.f, a1 = 0.f, a2 = 0.f, a3 = 0.f;
#pragma unroll 2
    for (int kc = 0; kc < 512; kc += 8) {
      int g0 = kc >> 2;
      float4 h0 = lds4[bbase + (g0 ^ bsw)];
      float4 h1 = lds4[bbase + ((g0 + 1) ^ bsw)];
      float4 wa0 = *(const float4*)(wr0 + kc), wb0 = *(const float4*)(wr0 + kc + 4);
      float4 wa1 = *(const float4*)(wr1 + kc), wb1 = *(const float4*)(wr1 + kc + 4);
      float4 wa2 = *(const float4*)(wr2 + kc), wb2 = *(const float4*)(wr2 + kc + 4);
      float4 wa3 = *(const float4*)(wr3 + kc), wb3 = *(const float4*)(wr3 + kc + 4);
      a0 = fmaf(wa0.x, h0.x, a0); a0 = fmaf(wa0.y, h0.y, a0); a0 = fmaf(wa0.z, h0.z, a0); a0 = fmaf(wa0.w, h0.w, a0);
      a0 = fmaf(wb0.x, h1.x, a0); a0 = fmaf(wb0.y, h1.y, a0); a0 = fmaf(wb0.z, h1.z, a0); a0 = fmaf(wb0.w, h1.w, a0);
      a1 = fmaf(wa1.x, h0.x, a1); a1 = fmaf(wa1.y, h0.y, a1); a1 = fmaf(wa1.z, h0.z, a1); a1 = fmaf(wa1.w, h0.w, a1);
      a1 = fmaf(wb1.x, h1.x, a1); a1 = fmaf(wb1.y, h1.y, a1); a1 = fmaf(wb1.z, h1.z, a1); a1 = fmaf(wb1.w, h1.w, a1);
      a2 = fmaf(wa2.x, h0.x, a2); a2 = fmaf(wa2.y, h0.y, a2); a2 = fmaf(wa2.z, h0.z, a2); a2 = fmaf(wa2.w, h0.w, a2);
      a2 = fmaf(wb2.x, h1.x, a2); a2 = fmaf(wb2.y, h1.y, a2); a2 = fmaf(wb2.z, h1.z, a2); a2 = fmaf(wb2.w, h1.w, a2);
      a3 = fmaf(wa3.x, h0.x, a3); a3 = fmaf(wa3.y, h0.y, a3); a3 = fmaf(wa3.z, h0.z, a3); a3 = fmaf(wa3.w, h0.w, a3);
      a3 = fmaf(wb3.x, h1.x, a3); a3 = fmaf(wb3.y, h1.y, a3); a3 = fmaf(wb3.z, h1.z, a3); a3 = fmaf(wb3.w, h1.w, a3);
    }
    size_t xb = (size_t)(d * 32 + tl) * 2048;
    float pre0 = a0 + XG[(xb + 0    + j) * 64 + b];
    float pre1 = a1 + XG[(xb + 512  + j) * 64 + b];
    float pre2 = a2 + XG[(xb + 1024 + j) * 64 + b];
    float pre3 = a3 + XG[(xb + 1536 + j) * 64 + b];
    float ig = sigm(pre0), fg = sigm(pre1), gg = tanhf(pre2), og = sigm(pre3);
    c = fmaf(fg, c, ig * gg);
    float h = og * tanhf(c);
    int pos = d ? (511 - t) : t;
    OUTT[((size_t)(d * 512 + pos) * 512 + j) * 64 + b] = h;
    lds[32768 + b * 5 + wid] = h;
    __syncthreads();
    {
      int bb = tid >> 2, jq = tid & 3;
      HT[(size_t)((p ^ 1) * 2 + d) * 32768 + (size_t)bb * 512 + m * 4 + jq] = lds[32768 + bb * 5 + jq];
    }
    grid.sync();
  }
  Cws[(size_t)(d * 512 + j) * 64 + b] = c;
}

// ---------------- K3a: last-row masked scores ST[t][b] ----------------
__global__ void __launch_bounds__(256) k3a_scores(const float* __restrict__ OUTT, float* __restrict__ ST) {
  int wid = RFL((int)(threadIdx.x >> 6));
  int b = threadIdx.x & 63;
  int t = blockIdx.x * 4 + wid;
  float acc = 0.f;
  for (int dd = 0; dd < 2; ++dd) {
    size_t bt = (size_t)(dd * 512 + t)   * 512;
    size_t bl = (size_t)(dd * 512 + 511) * 512;
    for (int jj = 0; jj < 512; ++jj)
      acc = fmaf(OUTT[(bt + jj) * 64 + b], OUTT[(bl + jj) * 64 + b], acc);
  }
  float sc = acc * (1.0f / 32.0f);
  ST[t * 64 + b] = (sc > 0.1f) ? sc : -1000000.0f;
}

// ---------------- K3b: softmax over t per batch ----------------
__global__ void __launch_bounds__(64) k3b_softmax(const float* __restrict__ ST, float* __restrict__ WT) {
  int b = threadIdx.x;
  float mx = -3.0e38f;
  for (int t = 0; t < 512; ++t) mx = fmaxf(mx, ST[t * 64 + b]);
  float sum = 0.f;
  for (int t = 0; t < 512; ++t) sum += __expf(ST[t * 64 + b] - mx);
  float inv = 1.0f / sum;
  for (int t = 0; t < 512; ++t) WT[t * 64 + b] = __expf(ST[t * 64 + b] - mx) * inv;
}

// ---------------- K3c: context CTX[d*512+j][b] ----------------
__global__ void __launch_bounds__(256) k3c_ctx(const float* __restrict__ OUTT,
    const float* __restrict__ WT, float* __restrict__ CTX) {
  int bq = blockIdx.x;                  // 256: d(1b) x 128 j-quads
  int d = bq >> 7, j0 = (bq & 127) * 4;
  int wid = RFL((int)(threadIdx.x >> 6));
  int b = threadIdx.x & 63;
  int j = j0 + wid;
  float acc = 0.f;
  for (int t = 0; t < 512; ++t)
    acc = fmaf(WT[t * 64 + b], OUTT[((size_t)(d * 512 + t) * 512 + j) * 64 + b], acc);
  CTX[(size_t)(d * 512 + j) * 64 + b] = acc;
}

// ---------------- K3d-pre: transpose W_out[256][1024] -> WoT[1024][256] ----------------
__global__ void __launch_bounds__(256) k3dpre(const float* __restrict__ Wout, float* __restrict__ WoT) {
  int o = threadIdx.x;
  int k0 = blockIdx.x * 64;
  for (int k = k0; k < k0 + 64; ++k)
    WoT[k * 256 + o] = Wout[(size_t)o * 1024 + k];
}

// ---------------- K3d: y[b][o] = ctx[b] . WoT[:,o] + b_out[o] ----------------
__global__ void __launch_bounds__(256) k3d_y(const float* __restrict__ CTX,
    const float* __restrict__ WoT, const float* __restrict__ bout, float* __restrict__ y) {
  __shared__ float lc[1024];
  int b = blockIdx.x, o = threadIdx.x;
  for (int k = threadIdx.x; k < 1024; k += 256) lc[k] = CTX[(size_t)k * 64 + b];
  __syncthreads();
  float acc = bout[o];
  for (int k = 0; k < 1024; ++k) acc = fmaf(lc[k], WoT[k * 256 + o], acc);
  y[b * 256 + o] = acc;
}

extern "C" void kernel_launch(void* const* d_in, const int* in_sizes, int n_in,
                              void* d_out, int out_size, void* d_ws, size_t ws_size,
                              hipStream_t stream) {
  (void)in_sizes; (void)n_in; (void)out_size; (void)ws_size;
  const float* inputs = (const float*)d_in[0];
  const float* Wih_f = (const float*)d_in[1];
  const float* Whh_f = (const float*)d_in[2];
  const float* bih_f = (const float*)d_in[3];
  const float* bhh_f = (const float*)d_in[4];
  const float* Wih_b = (const float*)d_in[5];
  const float* Whh_b = (const float*)d_in[6];
  const float* bih_b = (const float*)d_in[7];
  const float* bhh_b = (const float*)d_in[8];
  const float* Wout  = (const float*)d_in[9];
  const float* bout  = (const float*)d_in[10];
  float* y = (float*)d_out;

  float* ws = (float*)d_ws;
  size_t off = 0;
  float* XT4 = ws + off; off += (size_t)512 * 512 * 64;      // 16,777,216
  float* XG  = ws + off; off += (size_t)2 * 32 * 2048 * 64;  //  8,388,608
  float* OUTT= ws + off; off += (size_t)2 * 512 * 512 * 64;  // 33,554,432
  float* HT  = ws + off; off += (size_t)2 * 2 * 64 * 512;    //    131,072
  float* Cws = ws + off; off += (size_t)2 * 512 * 64;        //     65,536
  float* ST  = ws + off; off += (size_t)512 * 64;
  float* WT  = ws + off; off += (size_t)512 * 64;
  float* CTX = ws + off; off += (size_t)2 * 512 * 64;
  float* WoT = ws + off; off += (size_t)1024 * 256;

  hipMemsetAsync(HT,  0, (size_t)2 * 2 * 64 * 512 * sizeof(float), stream);
  hipMemsetAsync(Cws, 0, (size_t)2 * 512 * 64 * sizeof(float), stream);

  const int ldsK2 = (64 * 512 + 64 * 5) * 4;  // 132,352 B
  hipFuncSetAttribute(reinterpret_cast<const void*>(k2_rnn),
                      hipFuncAttributeMaxDynamicSharedMemorySize, ldsK2);

  k0_transpose<<<2048, 256, 0, stream>>>(inputs, XT4);

  for (int c = 0; c < 16; ++c) {
    int c0 = c * 32;
    k1_xg<<<1024, 256, 0, stream>>>(XT4, Wih_f, Wih_b, bih_f, bhh_f, bih_b, bhh_b, XG, c0);
    void* args[] = { (void*)&Whh_f, (void*)&Whh_b, (void*)&XG, (void*)&HT,
                     (void*)&OUTT, (void*)&Cws, (void*)&c0 };
    hipLaunchCooperativeKernel(reinterpret_cast<void*>(k2_rnn),
                               dim3(256), dim3(256), args, ldsK2, stream);
  }

  k3a_scores<<<128, 256, 0, stream>>>(OUTT, ST);
  k3b_softmax<<<1, 64, 0, stream>>>(ST, WT);
  k3c_ctx<<<256, 256, 0, stream>>>(OUTT, WT, CTX);
  k3dpre<<<16, 256, 0, stream>>>(Wout, WoT);
  k3d_y<<<64, 256, 0, stream>>>(CTX, WoT, bout, y);
}

// Round 3
// 16322.984 us; speedup vs baseline: 1.5712x; 1.5712x over previous
//
#include <hip/hip_runtime.h>
#include <hip/hip_cooperative_groups.h>

#define RFL(x) __builtin_amdgcn_readfirstlane(x)

__device__ __forceinline__ float sigm(float x) { return 1.0f / (1.0f + __expf(-x)); }

// ---------------- K0: transpose inputs (B,S,512) -> XT4[s][k/4][b][4] ----------------
__global__ void __launch_bounds__(256) k0_transpose(const float* __restrict__ in, float* __restrict__ XT4) {
  __shared__ float lds[32 * 260];
  int blk = blockIdx.x;            // s(512) * kh(2) * bh(2)
  int s  = blk >> 2;
  int kh = (blk >> 1) & 1;
  int bh = blk & 1;
  int t = threadIdx.x;
  const float4* in4 = (const float4*)in;
  for (int pass = 0; pass < 8; ++pass) {
    int q = pass * 256 + t;        // f4 over [32 b][64 k4]
    int bl = q >> 6, k4 = q & 63;
    float4 v = in4[ ((size_t)((bh * 32 + bl) * 512 + s)) * 128 + kh * 64 + k4 ];
    *(float4*)&lds[bl * 260 + k4 * 4] = v;
  }
  __syncthreads();
  float4* out4 = (float4*)XT4;
  for (int pass = 0; pass < 8; ++pass) {
    int q = pass * 256 + t;        // f4 over [64 g4][32 b]
    int g4 = q >> 5, bl = q & 31;
    float4 v = *(const float4*)&lds[bl * 260 + g4 * 4];
    out4[ ((size_t)s * 128 + kh * 64 + g4) * 64 + bh * 32 + bl ] = v;
  }
}

// ---------------- K1: xg chunk producer. XG[d][tl][2048 rows][64 b] ----------------
// grid 1024: wg = d(1b) | gs(7b) | s8(2b); 4 waves = 4 step-pairs; lane = b
// W slice (16 rows x 512) staged in LDS, read as wave-uniform broadcasts.
__global__ void __launch_bounds__(256) k1_xg(const float* __restrict__ XT4,
    const float* __restrict__ Wih_f, const float* __restrict__ Wih_b,
    const float* __restrict__ bih_f, const float* __restrict__ bhh_f,
    const float* __restrict__ bih_b, const float* __restrict__ bhh_b,
    float* __restrict__ XG, int c0) {
  __shared__ float4 wlds4[2048];            // 16 rows x 128 f4 = 32 KB
  int wg = blockIdx.x;
  int d  = wg & 1;
  int gs = (wg >> 1) & 127;
  int s8 = wg >> 8;                         // [0,4)
  int tid = threadIdx.x;
  int wid = RFL((int)(tid >> 6));
  int b = tid & 63;
  int tl0 = s8 * 8 + wid * 2;
  int t0 = c0 + tl0;
  int pos0 = d ? (511 - t0) : t0;
  int pos1 = d ? (511 - (t0 + 1)) : (t0 + 1);
  const float* Wih = d ? Wih_b : Wih_f;
  const float* bih = d ? bih_b : bih_f;
  const float* bhh = d ? bhh_b : bhh_f;
  const float* __restrict__ W0 = Wih + (size_t)gs * 16 * 512;
#pragma unroll
  for (int i = 0; i < 8; ++i) {
    int q = i * 256 + tid;                  // r = q>>7, kg = q&127
    wlds4[q] = *(const float4*)&W0[(size_t)(q >> 7) * 512 + (size_t)(q & 127) * 4];
  }
  float acc0[16], acc1[16];
#pragma unroll
  for (int r = 0; r < 16; ++r) {
    float bb = bih[gs * 16 + r] + bhh[gs * 16 + r];
    acc0[r] = bb; acc1[r] = bb;
  }
  __syncthreads();
  const float4* X4 = (const float4*)XT4;
  for (int kc = 0; kc < 512; kc += 4) {
    float4 x0 = X4[((size_t)pos0 * 128 + (kc >> 2)) * 64 + b];
    float4 x1 = X4[((size_t)pos1 * 128 + (kc >> 2)) * 64 + b];
#pragma unroll
    for (int r = 0; r < 16; ++r) {
      float4 wv = wlds4[r * 128 + (kc >> 2)];
      acc0[r] = fmaf(wv.x, x0.x, acc0[r]); acc0[r] = fmaf(wv.y, x0.y, acc0[r]);
      acc0[r] = fmaf(wv.z, x0.z, acc0[r]); acc0[r] = fmaf(wv.w, x0.w, acc0[r]);
      acc1[r] = fmaf(wv.x, x1.x, acc1[r]); acc1[r] = fmaf(wv.y, x1.y, acc1[r]);
      acc1[r] = fmaf(wv.z, x1.z, acc1[r]); acc1[r] = fmaf(wv.w, x1.w, acc1[r]);
    }
  }
#pragma unroll
  for (int r = 0; r < 16; ++r) {
    XG[((size_t)(d * 32 + tl0)     * 2048 + gs * 16 + r) * 64 + b] = acc0[r];
    XG[((size_t)(d * 32 + tl0 + 1) * 2048 + gs * 16 + r) * 64 + b] = acc1[r];
  }
}

// ---------------- K2: cooperative recurrence, 32 steps per launch ----------------
// 256 blocks: d = bid&1, blk = bid>>1 (128/dir, each owns j0=blk*4 .. j0+3).
// 512 threads = 8 waves = (rg in {0,1} row-groups of 8) x (kq in {0..3} k-quarters of 128).
// LDS 160 KB exactly: h[64 b][128 f4] XOR-swizzled (128 KB) + W[16 rows][128 f4] (32 KB).
// partials (16 KB) OVERLAY the first 16 KB of the h region (h dead after FMA phase).
// HTQ global layout: [parity][dir][k4=j>>2][b][j&3]  (dense 16B-granular writes).
__global__ void __launch_bounds__(512, 1) k2_rnn(const float* __restrict__ Whh_f,
    const float* __restrict__ Whh_b, const float* __restrict__ XG,
    float* __restrict__ HTQ, float* __restrict__ OUTT, float* __restrict__ Cws,
    unsigned int* __restrict__ Bar, int c0) {
  extern __shared__ float lds[];
  float4* hlds4 = (float4*)lds;                 // 8192 f4 = 128 KB
  float4* wlds4 = (float4*)(lds + 32768);       // 2048 f4 = 32 KB
  float*  part  = lds;                          // overlay, 4096 f32 = 16 KB
  int bid = blockIdx.x;
  int d = bid & 1, blk = bid >> 1;
  int j0 = blk * 4;
  int tid = threadIdx.x;
  int wid = RFL((int)(tid >> 6));
  int lane = tid & 63;
  int rg = wid & 1, kq = wid >> 1;
  const float* Whh = d ? Whh_b : Whh_f;

  // stage W once: block-row r = g*4 + jl <-> global row g*512 + j0 + jl
#pragma unroll
  for (int i = 0; i < 4; ++i) {
    int q = i * 512 + tid;
    int r = q >> 7, kg = q & 127;
    int g = r >> 2, jl = r & 3;
    wlds4[r * 128 + kg] = *(const float4*)(Whh + ((size_t)(g * 512 + j0 + jl)) * 512 + kg * 4);
  }
  int jl_g = tid >> 6;           // gate threads: tid<256 -> (jl_g in 0..3, b_g in 0..63)
  int b_g = tid & 63;
  float c = 0.f;
  if (tid < 256) c = Cws[(size_t)(d * 512 + j0 + jl_g) * 64 + b_g];
  __syncthreads();

  unsigned int* subc  = Bar + (size_t)d * 256;     // 16 counters, 64 B apart
  unsigned int* rootc = Bar + 512 + (size_t)d * 16;
  int bbase = lane * 128, bsw = lane & 7;

  for (int tl = 0; tl < 32; ++tl) {
    int t = c0 + tl, p = t & 1;
    // stage full h (8192 f4): coalesced global f4; LDS [b][k4] with k4 ^= (b&7)
    const float4* src = (const float4*)(HTQ + (size_t)(p * 2 + d) * 32768);
#pragma unroll
    for (int i = 0; i < 16; ++i) {
      int q = i * 512 + tid;
      int b = q & 63, k4 = q >> 6;
      hlds4[b * 128 + (k4 ^ (b & 7))] = src[q];
    }
    // prefetch gate biases (independent of h)
    float xg0 = 0.f, xg1 = 0.f, xg2 = 0.f, xg3 = 0.f;
    if (tid < 256) {
      size_t xb = (size_t)(d * 32 + tl) * 2048;
      xg0 = XG[(xb + 0    + j0 + jl_g) * 64 + b_g];
      xg1 = XG[(xb + 512  + j0 + jl_g) * 64 + b_g];
      xg2 = XG[(xb + 1024 + j0 + jl_g) * 64 + b_g];
      xg3 = XG[(xb + 1536 + j0 + jl_g) * 64 + b_g];
    }
    __syncthreads();
    // partial dot: 8 block-rows (rg*8..+7), k-quarter kq (128 k)
    float acc[8] = {0.f, 0.f, 0.f, 0.f, 0.f, 0.f, 0.f, 0.f};
#pragma unroll 2
    for (int ik = 0; ik < 16; ++ik) {
      int g0 = kq * 32 + ik * 2;
      float4 h0 = hlds4[bbase + (g0 ^ bsw)];
      float4 h1 = hlds4[bbase + ((g0 + 1) ^ bsw)];
#pragma unroll
      for (int r = 0; r < 8; ++r) {
        float4 wa = wlds4[(rg * 8 + r) * 128 + g0];
        float4 wb = wlds4[(rg * 8 + r) * 128 + g0 + 1];
        acc[r] = fmaf(wa.x, h0.x, acc[r]); acc[r] = fmaf(wa.y, h0.y, acc[r]);
        acc[r] = fmaf(wa.z, h0.z, acc[r]); acc[r] = fmaf(wa.w, h0.w, acc[r]);
        acc[r] = fmaf(wb.x, h1.x, acc[r]); acc[r] = fmaf(wb.y, h1.y, acc[r]);
        acc[r] = fmaf(wb.z, h1.z, acc[r]); acc[r] = fmaf(wb.w, h1.w, acc[r]);
      }
    }
    __syncthreads();   // all h reads done before partials overlay the h region
#pragma unroll
    for (int r = 0; r < 8; ++r) part[(kq * 16 + rg * 8 + r) * 64 + lane] = acc[r];
    __syncthreads();
    if (tid < 256) {
      float pre0 = xg0, pre1 = xg1, pre2 = xg2, pre3 = xg3;
#pragma unroll
      for (int kqi = 0; kqi < 4; ++kqi) {
        pre0 += part[(kqi * 16 + 0  + jl_g) * 64 + b_g];
        pre1 += part[(kqi * 16 + 4  + jl_g) * 64 + b_g];
        pre2 += part[(kqi * 16 + 8  + jl_g) * 64 + b_g];
        pre3 += part[(kqi * 16 + 12 + jl_g) * 64 + b_g];
      }
      float ig = sigm(pre0), fg = sigm(pre1), gg = tanhf(pre2), og = sigm(pre3);
      c = fmaf(fg, c, ig * gg);
      float h = og * tanhf(c);
      int pos = d ? (511 - t) : t;
      OUTT[((size_t)(d * 512 + pos) * 512 + j0 + jl_g) * 64 + b_g] = h;
      // HTQ: word index ((j>>2)*64 + b)*4 + (j&3), j = j0+jl_g, j>>2 == blk
      HTQ[(size_t)((p ^ 1) * 2 + d) * 32768 + (size_t)(blk * 64 + b_g) * 4 + jl_g] = h;
    }
    __syncthreads();   // each wave drains vmcnt -> block's stores are in L2
    if (tid == 0) {
      __threadfence(); // release: write back L2 to coherence point
      unsigned int step1 = (unsigned int)(t + 1);
      unsigned int old = atomicAdd(&subc[(blk & 15) * 16], 1u);
      if (old == 8u * step1 - 1u) atomicAdd(rootc, 1u);
      while (__hip_atomic_load(rootc, __ATOMIC_RELAXED, __HIP_MEMORY_SCOPE_AGENT) < 16u * step1) {
        __builtin_amdgcn_s_sleep(1);
      }
      __threadfence(); // acquire: invalidate stale L1/L2
    }
    __syncthreads();
  }
  if (tid < 256) Cws[(size_t)(d * 512 + j0 + jl_g) * 64 + b_g] = c;
}

// ---------------- K3a: last-row masked scores ST[t][b] ----------------
__global__ void __launch_bounds__(256) k3a_scores(const float* __restrict__ OUTT, float* __restrict__ ST) {
  int wid = RFL((int)(threadIdx.x >> 6));
  int b = threadIdx.x & 63;
  int t = blockIdx.x * 4 + wid;
  float acc = 0.f;
  for (int dd = 0; dd < 2; ++dd) {
    size_t bt = (size_t)(dd * 512 + t)   * 512;
    size_t bl = (size_t)(dd * 512 + 511) * 512;
    for (int jj = 0; jj < 512; ++jj)
      acc = fmaf(OUTT[(bt + jj) * 64 + b], OUTT[(bl + jj) * 64 + b], acc);
  }
  float sc = acc * (1.0f / 32.0f);
  ST[t * 64 + b] = (sc > 0.1f) ? sc : -1000000.0f;
}

// ---------------- K3b: softmax over t per batch ----------------
__global__ void __launch_bounds__(64) k3b_softmax(const float* __restrict__ ST, float* __restrict__ WT) {
  int b = threadIdx.x;
  float mx = -3.0e38f;
  for (int t = 0; t < 512; ++t) mx = fmaxf(mx, ST[t * 64 + b]);
  float sum = 0.f;
  for (int t = 0; t < 512; ++t) sum += __expf(ST[t * 64 + b] - mx);
  float inv = 1.0f / sum;
  for (int t = 0; t < 512; ++t) WT[t * 64 + b] = __expf(ST[t * 64 + b] - mx) * inv;
}

// ---------------- K3c: context CTX[d*512+j][b] ----------------
__global__ void __launch_bounds__(256) k3c_ctx(const float* __restrict__ OUTT,
    const float* __restrict__ WT, float* __restrict__ CTX) {
  int bq = blockIdx.x;                  // 256: d(1b) x 128 j-quads
  int d = bq >> 7, j0 = (bq & 127) * 4;
  int wid = RFL((int)(threadIdx.x >> 6));
  int b = threadIdx.x & 63;
  int j = j0 + wid;
  float acc = 0.f;
  for (int t = 0; t < 512; ++t)
    acc = fmaf(WT[t * 64 + b], OUTT[((size_t)(d * 512 + t) * 512 + j) * 64 + b], acc);
  CTX[(size_t)(d * 512 + j) * 64 + b] = acc;
}

// ---------------- K3d-pre: transpose W_out[256][1024] -> WoT[1024][256] ----------------
__global__ void __launch_bounds__(256) k3dpre(const float* __restrict__ Wout, float* __restrict__ WoT) {
  int o = threadIdx.x;
  int k0 = blockIdx.x * 64;
  for (int k = k0; k < k0 + 64; ++k)
    WoT[k * 256 + o] = Wout[(size_t)o * 1024 + k];
}

// ---------------- K3d: y[b][o] = ctx[b] . WoT[:,o] + b_out[o] ----------------
__global__ void __launch_bounds__(256) k3d_y(const float* __restrict__ CTX,
    const float* __restrict__ WoT, const float* __restrict__ bout, float* __restrict__ y) {
  __shared__ float lc[1024];
  int b = blockIdx.x, o = threadIdx.x;
  for (int k = threadIdx.x; k < 1024; k += 256) lc[k] = CTX[(size_t)k * 64 + b];
  __syncthreads();
  float acc = bout[o];
  for (int k = 0; k < 1024; ++k) acc = fmaf(lc[k], WoT[k * 256 + o], acc);
  y[b * 256 + o] = acc;
}

extern "C" void kernel_launch(void* const* d_in, const int* in_sizes, int n_in,
                              void* d_out, int out_size, void* d_ws, size_t ws_size,
                              hipStream_t stream) {
  (void)in_sizes; (void)n_in; (void)out_size; (void)ws_size;
  const float* inputs = (const float*)d_in[0];
  const float* Wih_f = (const float*)d_in[1];
  const float* Whh_f = (const float*)d_in[2];
  const float* bih_f = (const float*)d_in[3];
  const float* bhh_f = (const float*)d_in[4];
  const float* Wih_b = (const float*)d_in[5];
  const float* Whh_b = (const float*)d_in[6];
  const float* bih_b = (const float*)d_in[7];
  const float* bhh_b = (const float*)d_in[8];
  const float* Wout  = (const float*)d_in[9];
  const float* bout  = (const float*)d_in[10];
  float* y = (float*)d_out;

  float* ws = (float*)d_ws;
  size_t off = 0;
  float* XT4 = ws + off; off += (size_t)512 * 512 * 64;
  float* XG  = ws + off; off += (size_t)2 * 32 * 2048 * 64;
  float* OUTT= ws + off; off += (size_t)2 * 512 * 512 * 64;
  float* HTQ = ws + off; off += (size_t)2 * 2 * 64 * 512;
  float* Cws = ws + off; off += (size_t)2 * 512 * 64;
  float* ST  = ws + off; off += (size_t)512 * 64;
  float* WT  = ws + off; off += (size_t)512 * 64;
  float* CTX = ws + off; off += (size_t)2 * 512 * 64;
  float* WoT = ws + off; off += (size_t)1024 * 256;
  unsigned int* Bar = (unsigned int*)(ws + off); off += 1024;

  hipMemsetAsync(HTQ, 0, (size_t)2 * 2 * 64 * 512 * sizeof(float), stream);
  hipMemsetAsync(Cws, 0, (size_t)2 * 512 * 64 * sizeof(float), stream);
  hipMemsetAsync(Bar, 0, 4096, stream);

  const int ldsK2 = (32768 + 8192) * 4;   // 163,840 B = 160 KB exactly
  hipFuncSetAttribute(reinterpret_cast<const void*>(k2_rnn),
                      hipFuncAttributeMaxDynamicSharedMemorySize, ldsK2);

  k0_transpose<<<2048, 256, 0, stream>>>(inputs, XT4);

  for (int c = 0; c < 16; ++c) {
    int c0 = c * 32;
    k1_xg<<<1024, 256, 0, stream>>>(XT4, Wih_f, Wih_b, bih_f, bhh_f, bih_b, bhh_b, XG, c0);
    void* args[] = { (void*)&Whh_f, (void*)&Whh_b, (void*)&XG, (void*)&HTQ,
                     (void*)&OUTT, (void*)&Cws, (void*)&Bar, (void*)&c0 };
    hipLaunchCooperativeKernel(reinterpret_cast<void*>(k2_rnn),
                               dim3(256), dim3(512), args, ldsK2, stream);
  }

  k3a_scores<<<128, 256, 0, stream>>>(OUTT, ST);
  k3b_softmax<<<1, 64, 0, stream>>>(ST, WT);
  k3c_ctx<<<256, 256, 0, stream>>>(OUTT, WT, CTX);
  k3dpre<<<16, 256, 0, stream>>>(Wout, WoT);
  k3d_y<<<64, 256, 0, stream>>>(CTX, WoT, bout, y);
}

// Round 4
// 8617.892 us; speedup vs baseline: 2.9759x; 1.8941x over previous
//
#include <hip/hip_runtime.h>
#include <hip/hip_cooperative_groups.h>
#include <hip/hip_bf16.h>

#define RFL(x) __builtin_amdgcn_readfirstlane(x)

typedef __attribute__((ext_vector_type(8))) short bf16x8;
typedef __attribute__((ext_vector_type(4))) float f32x4;

__device__ __forceinline__ float sigm(float x) { return 1.0f / (1.0f + __expf(-x)); }

__device__ __forceinline__ ushort bf16_rne(float x) {
  __hip_bfloat16 h = __float2bfloat16(x);
  return *reinterpret_cast<ushort*>(&h);
}
__device__ __forceinline__ float bf16_tof(ushort u) {
  __hip_bfloat16 h = *reinterpret_cast<__hip_bfloat16*>(&u);
  return __bfloat162float(h);
}

// ---------------- K0: transpose inputs (B,S,512) -> XT4[s][k/4][b][4] ----------------
__global__ void __launch_bounds__(256) k0_transpose(const float* __restrict__ in, float* __restrict__ XT4) {
  __shared__ float lds[32 * 260];
  int blk = blockIdx.x;            // s(512) * kh(2) * bh(2)
  int s  = blk >> 2;
  int kh = (blk >> 1) & 1;
  int bh = blk & 1;
  int t = threadIdx.x;
  const float4* in4 = (const float4*)in;
  for (int pass = 0; pass < 8; ++pass) {
    int q = pass * 256 + t;        // f4 over [32 b][64 k4]
    int bl = q >> 6, k4 = q & 63;
    float4 v = in4[ ((size_t)((bh * 32 + bl) * 512 + s)) * 128 + kh * 64 + k4 ];
    *(float4*)&lds[bl * 260 + k4 * 4] = v;
  }
  __syncthreads();
  float4* out4 = (float4*)XT4;
  for (int pass = 0; pass < 8; ++pass) {
    int q = pass * 256 + t;        // f4 over [64 g4][32 b]
    int g4 = q >> 5, bl = q & 31;
    float4 v = *(const float4*)&lds[bl * 260 + g4 * 4];
    out4[ ((size_t)s * 128 + kh * 64 + g4) * 64 + bh * 32 + bl ] = v;
  }
}

// ---------------- KW: split W_hh (both dirs) into bf16 hi|lo: WBS[d][2048 rows][1024 ccat] ----------------
__global__ void __launch_bounds__(256) kw_split(const float* __restrict__ Whh_f,
    const float* __restrict__ Whh_b, ushort* __restrict__ WBS) {
  int idx = blockIdx.x * 256 + threadIdx.x;   // [0, 524288): d(1) x row(2048) x k4(128)
  int d = idx >> 18;
  int r = (idx >> 7) & 2047;
  int k4 = idx & 127;
  const float* W = d ? Whh_b : Whh_f;
  float4 v = *(const float4*)&W[(size_t)r * 512 + k4 * 4];
  ushort h0 = bf16_rne(v.x), h1 = bf16_rne(v.y), h2 = bf16_rne(v.z), h3 = bf16_rne(v.w);
  ushort l0 = bf16_rne(v.x - bf16_tof(h0));
  ushort l1 = bf16_rne(v.y - bf16_tof(h1));
  ushort l2 = bf16_rne(v.z - bf16_tof(h2));
  ushort l3 = bf16_rne(v.w - bf16_tof(h3));
  ushort* base = WBS + (size_t)d * 2048 * 1024 + (size_t)r * 1024;
  uint2 HI = { (uint)h0 | ((uint)h1 << 16), (uint)h2 | ((uint)h3 << 16) };
  uint2 LO = { (uint)l0 | ((uint)l1 << 16), (uint)l2 | ((uint)l3 << 16) };
  *(uint2*)(base + k4 * 4) = HI;
  *(uint2*)(base + 512 + k4 * 4) = LO;
}

// ---------------- K1: xg chunk producer. XG[d][tl][2048 rows][64 b] ----------------
__global__ void __launch_bounds__(256) k1_xg(const float* __restrict__ XT4,
    const float* __restrict__ Wih_f, const float* __restrict__ Wih_b,
    const float* __restrict__ bih_f, const float* __restrict__ bhh_f,
    const float* __restrict__ bih_b, const float* __restrict__ bhh_b,
    float* __restrict__ XG, int c0) {
  __shared__ float4 wlds4[2048];            // 16 rows x 128 f4 = 32 KB
  int wg = blockIdx.x;
  int d  = wg & 1;
  int gs = (wg >> 1) & 127;
  int s8 = wg >> 8;                         // [0,4)
  int tid = threadIdx.x;
  int wid = RFL((int)(tid >> 6));
  int b = tid & 63;
  int tl0 = s8 * 8 + wid * 2;
  int t0 = c0 + tl0;
  int pos0 = d ? (511 - t0) : t0;
  int pos1 = d ? (511 - (t0 + 1)) : (t0 + 1);
  const float* Wih = d ? Wih_b : Wih_f;
  const float* bih = d ? bih_b : bih_f;
  const float* bhh = d ? bhh_b : bhh_f;
  const float* __restrict__ W0 = Wih + (size_t)gs * 16 * 512;
#pragma unroll
  for (int i = 0; i < 8; ++i) {
    int q = i * 256 + tid;
    wlds4[q] = *(const float4*)&W0[(size_t)(q >> 7) * 512 + (size_t)(q & 127) * 4];
  }
  float acc0[16], acc1[16];
#pragma unroll
  for (int r = 0; r < 16; ++r) {
    float bb = bih[gs * 16 + r] + bhh[gs * 16 + r];
    acc0[r] = bb; acc1[r] = bb;
  }
  __syncthreads();
  const float4* X4 = (const float4*)XT4;
  for (int kc = 0; kc < 512; kc += 4) {
    float4 x0 = X4[((size_t)pos0 * 128 + (kc >> 2)) * 64 + b];
    float4 x1 = X4[((size_t)pos1 * 128 + (kc >> 2)) * 64 + b];
#pragma unroll
    for (int r = 0; r < 16; ++r) {
      float4 wv = wlds4[r * 128 + (kc >> 2)];
      acc0[r] = fmaf(wv.x, x0.x, acc0[r]); acc0[r] = fmaf(wv.y, x0.y, acc0[r]);
      acc0[r] = fmaf(wv.z, x0.z, acc0[r]); acc0[r] = fmaf(wv.w, x0.w, acc0[r]);
      acc1[r] = fmaf(wv.x, x1.x, acc1[r]); acc1[r] = fmaf(wv.y, x1.y, acc1[r]);
      acc1[r] = fmaf(wv.z, x1.z, acc1[r]); acc1[r] = fmaf(wv.w, x1.w, acc1[r]);
    }
  }
#pragma unroll
  for (int r = 0; r < 16; ++r) {
    XG[((size_t)(d * 32 + tl0)     * 2048 + gs * 16 + r) * 64 + b] = acc0[r];
    XG[((size_t)(d * 32 + tl0 + 1) * 2048 + gs * 16 + r) * 64 + b] = acc1[r];
  }
}

// ---------------- K2: cooperative recurrence, MFMA split-bf16, 32 steps per launch ----------------
// 64 blocks: d = bid&1, jt = bid>>1 (32 j-tiles of 16 per dir). 512 threads = 8 waves = k-eighths.
// Wave kq owns ccat-slices c32 in {2kq, 2kq+1, 16+2kq, 16+2kq+1} (hi/lo paired -> 2-pass cross terms).
// A (W split) persistent in VGPRs; B (h split) preloaded to regs from swizzled LDS tile each step.
// LDS 160 KB: hcat bf16 [b64][ccat1024] (128 KB, byte ^= (b&31)<<4), overlaid by part f32 [kq8][g4][b64][20].
__global__ void __launch_bounds__(512, 1) k2_rnn(const ushort* __restrict__ WBS,
    const float* __restrict__ XG, float* __restrict__ HTQ, float* __restrict__ OUTT,
    float* __restrict__ Cws, unsigned int* __restrict__ Bar, int c0) {
  extern __shared__ float lds[];
  float* part = lds;
  char* ldsb = (char*)lds;
  int bid = blockIdx.x;
  int d = bid & 1, jt = bid >> 1;
  int tid = threadIdx.x;
  int kq = RFL((int)(tid >> 6));
  int lane = tid & 63;
  int l15 = lane & 15, l4 = lane >> 4;

  const int c32s[4] = { 2*kq, 2*kq + 1, 16 + 2*kq, 16 + 2*kq + 1 };

  // A-frag preload (once per dispatch): lane l: row g*512 + jt*16 + l15, c = c32*32 + 8*l4
  bf16x8 Afr[4][4];
  const ushort* WB = WBS + (size_t)d * 2048 * 1024;
#pragma unroll
  for (int g = 0; g < 4; ++g)
#pragma unroll
    for (int s = 0; s < 4; ++s) {
      int row = g * 512 + jt * 16 + l15;
      int c = c32s[s] * 32 + 8 * l4;
      Afr[g][s] = *(const bf16x8*)(WB + (size_t)row * 1024 + c);
    }

  // gate-thread mapping: (jj = tid&15, b = tid>>4) and (jj, b+32)
  int jj_g = tid & 15, b_g = tid >> 4;
  int j_g = jt * 16 + jj_g;
  float c_a = Cws[(size_t)(d * 512 + j_g) * 64 + b_g];
  float c_b = Cws[(size_t)(d * 512 + j_g) * 64 + b_g + 32];

  unsigned int* subc  = Bar + (size_t)(d * 4 + (jt >> 3)) * 16;
  unsigned int* rootc = Bar + 128 + (size_t)d * 16;

  for (int tl = 0; tl < 32; ++tl) {
    int t = c0 + tl, p = t & 1;
    // ---- stage h -> hcat (split to hi/lo bf16), 8 iters: pairs of f4 (8 j values)
    const float4* src = (const float4*)(HTQ + (size_t)(p * 2 + d) * 32768);
#pragma unroll
    for (int i = 0; i < 8; ++i) {
      int q = i * 512 + tid;           // [0,4096): j8 = q>>6, b = q&63
      int j8 = q >> 6, b = q & 63;
      float4 a0 = src[(2 * j8) * 64 + b];
      float4 a1 = src[(2 * j8 + 1) * 64 + b];
      float hv[8] = { a0.x, a0.y, a0.z, a0.w, a1.x, a1.y, a1.z, a1.w };
      ushort hi[8], lo[8];
#pragma unroll
      for (int e = 0; e < 8; ++e) {
        hi[e] = bf16_rne(hv[e]);
        lo[e] = bf16_rne(hv[e] - bf16_tof(hi[e]));
      }
      uint4 HI = { (uint)hi[0] | ((uint)hi[1] << 16), (uint)hi[2] | ((uint)hi[3] << 16),
                   (uint)hi[4] | ((uint)hi[5] << 16), (uint)hi[6] | ((uint)hi[7] << 16) };
      uint4 LO = { (uint)lo[0] | ((uint)lo[1] << 16), (uint)lo[2] | ((uint)lo[3] << 16),
                   (uint)lo[4] | ((uint)lo[5] << 16), (uint)lo[6] | ((uint)lo[7] << 16) };
      int sw = (b & 31) << 4;
      *(uint4*)(ldsb + b * 2048 + ((j8 * 16) ^ sw)) = HI;
      *(uint4*)(ldsb + b * 2048 + ((1024 + j8 * 16) ^ sw)) = LO;
    }
    // prefetch gate biases (independent of h)
    float xg[4][2];
    {
      size_t xb = (size_t)(d * 32 + tl) * 2048;
#pragma unroll
      for (int g = 0; g < 4; ++g) {
        xg[g][0] = XG[(xb + g * 512 + j_g) * 64 + b_g];
        xg[g][1] = XG[(xb + g * 512 + j_g) * 64 + b_g + 32];
      }
    }
    __syncthreads();
    // ---- B-frag preload: lane l: b = bt*16 + l15, c = c32*32 + 8*l4
    bf16x8 Bfr[4][4];
#pragma unroll
    for (int bt = 0; bt < 4; ++bt) {
#pragma unroll
      for (int s = 0; s < 4; ++s) {
        int b = bt * 16 + l15;
        int cb = c32s[s] * 64 + 16 * l4;     // byte col = 2*c
        Bfr[bt][s] = *(const bf16x8*)(ldsb + b * 2048 + (cb ^ ((b & 31) << 4)));
      }
    }
    __syncthreads();   // hcat reads done before part overlays it
    // ---- MFMA: 2 passes (main: A[s]xB[s]; cross: A[s]xB[s^2])
    f32x4 acc[4][4];
#pragma unroll
    for (int g = 0; g < 4; ++g)
#pragma unroll
      for (int bt = 0; bt < 4; ++bt) acc[g][bt] = (f32x4){0.f, 0.f, 0.f, 0.f};
#pragma unroll
    for (int pass = 0; pass < 2; ++pass) {
#pragma unroll
      for (int s = 0; s < 4; ++s) {
        int bs = pass ? (s ^ 2) : s;
#pragma unroll
        for (int g = 0; g < 4; ++g)
#pragma unroll
          for (int bt = 0; bt < 4; ++bt)
            acc[g][bt] = __builtin_amdgcn_mfma_f32_16x16x32_bf16(
                Afr[g][s], Bfr[bt][bs], acc[g][bt], 0, 0, 0);
      }
    }
    // ---- part write: [kq][g][b][20], jj = 4*l4 + reg
#pragma unroll
    for (int g = 0; g < 4; ++g)
#pragma unroll
      for (int bt = 0; bt < 4; ++bt) {
        int w = ((kq * 4 + g) * 64 + bt * 16 + l15) * 20 + 4 * l4;
        *(f32x4*)&part[w] = acc[g][bt];
      }
    __syncthreads();
    // ---- gate phase: all 512 threads, 2 units each
    int pos = d ? (511 - t) : t;
#pragma unroll
    for (int u = 0; u < 2; ++u) {
      int b = b_g + 32 * u;
      float pre[4];
#pragma unroll
      for (int g = 0; g < 4; ++g) {
        float acc_s = xg[g][u];
#pragma unroll
        for (int kqi = 0; kqi < 8; ++kqi)
          acc_s += part[((kqi * 4 + g) * 64 + b) * 20 + jj_g];
        pre[g] = acc_s;
      }
      float ig = sigm(pre[0]), fg = sigm(pre[1]), gg = tanhf(pre[2]), og = sigm(pre[3]);
      float& cc = u ? c_b : c_a;
      cc = fmaf(fg, cc, ig * gg);
      float h = og * tanhf(cc);
      OUTT[((size_t)(d * 512 + pos) * 512 + j_g) * 64 + b] = h;
      HTQ[(size_t)((p ^ 1) * 2 + d) * 32768 +
          (size_t)((jt * 4 + (jj_g >> 2)) * 64 + b) * 4 + (jj_g & 3)] = h;
    }
    __syncthreads();   // all waves' stores drained (compiler: vmcnt(0) before barrier)
    if (tid == 0) {
      __threadfence();
      unsigned int step1 = (unsigned int)(t + 1);
      unsigned int old = atomicAdd(subc, 1u);
      if (old == 8u * step1 - 1u) atomicAdd(rootc, 1u);
      while (__hip_atomic_load(rootc, __ATOMIC_RELAXED, __HIP_MEMORY_SCOPE_AGENT) < 4u * step1) {
        __builtin_amdgcn_s_sleep(1);
      }
      __threadfence();
    }
    __syncthreads();
  }
  Cws[(size_t)(d * 512 + j_g) * 64 + b_g] = c_a;
  Cws[(size_t)(d * 512 + j_g) * 64 + b_g + 32] = c_b;
}

// ---------------- K3a: last-row masked scores ST[t][b] ----------------
__global__ void __launch_bounds__(256) k3a_scores(const float* __restrict__ OUTT, float* __restrict__ ST) {
  int wid = RFL((int)(threadIdx.x >> 6));
  int b = threadIdx.x & 63;
  int t = blockIdx.x * 4 + wid;
  float acc = 0.f;
  for (int dd = 0; dd < 2; ++dd) {
    size_t bt = (size_t)(dd * 512 + t)   * 512;
    size_t bl = (size_t)(dd * 512 + 511) * 512;
    for (int jj = 0; jj < 512; ++jj)
      acc = fmaf(OUTT[(bt + jj) * 64 + b], OUTT[(bl + jj) * 64 + b], acc);
  }
  float sc = acc * (1.0f / 32.0f);
  ST[t * 64 + b] = (sc > 0.1f) ? sc : -1000000.0f;
}

// ---------------- K3b: softmax over t per batch ----------------
__global__ void __launch_bounds__(64) k3b_softmax(const float* __restrict__ ST, float* __restrict__ WT) {
  int b = threadIdx.x;
  float mx = -3.0e38f;
  for (int t = 0; t < 512; ++t) mx = fmaxf(mx, ST[t * 64 + b]);
  float sum = 0.f;
  for (int t = 0; t < 512; ++t) sum += __expf(ST[t * 64 + b] - mx);
  float inv = 1.0f / sum;
  for (int t = 0; t < 512; ++t) WT[t * 64 + b] = __expf(ST[t * 64 + b] - mx) * inv;
}

// ---------------- K3c: context CTX[d*512+j][b] ----------------
__global__ void __launch_bounds__(256) k3c_ctx(const float* __restrict__ OUTT,
    const float* __restrict__ WT, float* __restrict__ CTX) {
  int bq = blockIdx.x;
  int d = bq >> 7, j0 = (bq & 127) * 4;
  int wid = RFL((int)(threadIdx.x >> 6));
  int b = threadIdx.x & 63;
  int j = j0 + wid;
  float acc = 0.f;
  for (int t = 0; t < 512; ++t)
    acc = fmaf(WT[t * 64 + b], OUTT[((size_t)(d * 512 + t) * 512 + j) * 64 + b], acc);
  CTX[(size_t)(d * 512 + j) * 64 + b] = acc;
}

// ---------------- K3d-pre: transpose W_out[256][1024] -> WoT[1024][256] ----------------
__global__ void __launch_bounds__(256) k3dpre(const float* __restrict__ Wout, float* __restrict__ WoT) {
  int o = threadIdx.x;
  int k0 = blockIdx.x * 64;
  for (int k = k0; k < k0 + 64; ++k)
    WoT[k * 256 + o] = Wout[(size_t)o * 1024 + k];
}

// ---------------- K3d: y[b][o] = ctx[b] . WoT[:,o] + b_out[o] ----------------
__global__ void __launch_bounds__(256) k3d_y(const float* __restrict__ CTX,
    const float* __restrict__ WoT, const float* __restrict__ bout, float* __restrict__ y) {
  __shared__ float lc[1024];
  int b = blockIdx.x, o = threadIdx.x;
  for (int k = threadIdx.x; k < 1024; k += 256) lc[k] = CTX[(size_t)k * 64 + b];
  __syncthreads();
  float acc = bout[o];
  for (int k = 0; k < 1024; ++k) acc = fmaf(lc[k], WoT[k * 256 + o], acc);
  y[b * 256 + o] = acc;
}

extern "C" void kernel_launch(void* const* d_in, const int* in_sizes, int n_in,
                              void* d_out, int out_size, void* d_ws, size_t ws_size,
                              hipStream_t stream) {
  (void)in_sizes; (void)n_in; (void)out_size; (void)ws_size;
  const float* inputs = (const float*)d_in[0];
  const float* Wih_f = (const float*)d_in[1];
  const float* Whh_f = (const float*)d_in[2];
  const float* bih_f = (const float*)d_in[3];
  const float* bhh_f = (const float*)d_in[4];
  const float* Wih_b = (const float*)d_in[5];
  const float* Whh_b = (const float*)d_in[6];
  const float* bih_b = (const float*)d_in[7];
  const float* bhh_b = (const float*)d_in[8];
  const float* Wout  = (const float*)d_in[9];
  const float* bout  = (const float*)d_in[10];
  float* y = (float*)d_out;

  float* ws = (float*)d_ws;
  size_t off = 0;
  float* XT4 = ws + off; off += (size_t)512 * 512 * 64;
  float* XG  = ws + off; off += (size_t)2 * 32 * 2048 * 64;
  float* OUTT= ws + off; off += (size_t)2 * 512 * 512 * 64;
  float* HTQ = ws + off; off += (size_t)2 * 2 * 64 * 512;
  float* Cws = ws + off; off += (size_t)2 * 512 * 64;
  float* ST  = ws + off; off += (size_t)512 * 64;
  float* WT  = ws + off; off += (size_t)512 * 64;
  float* CTX = ws + off; off += (size_t)2 * 512 * 64;
  float* WoT = ws + off; off += (size_t)1024 * 256;
  ushort* WBS = (ushort*)(ws + off); off += (size_t)2 * 2048 * 1024 / 2;  // 4M ushort
  unsigned int* Bar = (unsigned int*)(ws + off); off += 1024;

  hipMemsetAsync(HTQ, 0, (size_t)2 * 2 * 64 * 512 * sizeof(float), stream);
  hipMemsetAsync(Cws, 0, (size_t)2 * 512 * 64 * sizeof(float), stream);
  hipMemsetAsync(Bar, 0, 4096, stream);

  const int ldsK2 = 8 * 4 * 64 * 20 * 4;   // 163,840 B = 160 KB exactly
  hipFuncSetAttribute(reinterpret_cast<const void*>(k2_rnn),
                      hipFuncAttributeMaxDynamicSharedMemorySize, ldsK2);

  k0_transpose<<<2048, 256, 0, stream>>>(inputs, XT4);
  kw_split<<<2048, 256, 0, stream>>>(Whh_f, Whh_b, WBS);

  for (int c = 0; c < 16; ++c) {
    int c0 = c * 32;
    k1_xg<<<1024, 256, 0, stream>>>(XT4, Wih_f, Wih_b, bih_f, bhh_f, bih_b, bhh_b, XG, c0);
    void* args[] = { (void*)&WBS, (void*)&XG, (void*)&HTQ,
                     (void*)&OUTT, (void*)&Cws, (void*)&Bar, (void*)&c0 };
    hipLaunchCooperativeKernel(reinterpret_cast<void*>(k2_rnn),
                               dim3(64), dim3(512), args, ldsK2, stream);
  }

  k3a_scores<<<128, 256, 0, stream>>>(OUTT, ST);
  k3b_softmax<<<1, 64, 0, stream>>>(ST, WT);
  k3c_ctx<<<256, 256, 0, stream>>>(OUTT, WT, CTX);
  k3dpre<<<16, 256, 0, stream>>>(Wout, WoT);
  k3d_y<<<64, 256, 0, stream>>>(CTX, WoT, bout, y);
}

// Round 5
// 7891.062 us; speedup vs baseline: 3.2500x; 1.0921x over previous
//
#include <hip/hip_runtime.h>
#include <hip/hip_cooperative_groups.h>
#include <hip/hip_bf16.h>

#define RFL(x) __builtin_amdgcn_readfirstlane(x)

typedef __attribute__((ext_vector_type(8))) short bf16x8;
typedef __attribute__((ext_vector_type(4))) float f32x4;

__device__ __forceinline__ float sigm(float x) { return 1.0f / (1.0f + __expf(-x)); }

__device__ __forceinline__ ushort bf16_rne(float x) {
  __hip_bfloat16 h = __float2bfloat16(x);
  return *reinterpret_cast<ushort*>(&h);
}
__device__ __forceinline__ float bf16_tof(ushort u) {
  __hip_bfloat16 h = *reinterpret_cast<__hip_bfloat16*>(&u);
  return __bfloat162float(h);
}

// ---------------- K0: transpose inputs (B,S,512) -> XT4[s][k/4][b][4] ----------------
__global__ void __launch_bounds__(256) k0_transpose(const float* __restrict__ in, float* __restrict__ XT4) {
  __shared__ float lds[32 * 260];
  int blk = blockIdx.x;            // s(512) * kh(2) * bh(2)
  int s  = blk >> 2;
  int kh = (blk >> 1) & 1;
  int bh = blk & 1;
  int t = threadIdx.x;
  const float4* in4 = (const float4*)in;
  for (int pass = 0; pass < 8; ++pass) {
    int q = pass * 256 + t;        // f4 over [32 b][64 k4]
    int bl = q >> 6, k4 = q & 63;
    float4 v = in4[ ((size_t)((bh * 32 + bl) * 512 + s)) * 128 + kh * 64 + k4 ];
    *(float4*)&lds[bl * 260 + k4 * 4] = v;
  }
  __syncthreads();
  float4* out4 = (float4*)XT4;
  for (int pass = 0; pass < 8; ++pass) {
    int q = pass * 256 + t;        // f4 over [64 g4][32 b]
    int g4 = q >> 5, bl = q & 31;
    float4 v = *(const float4*)&lds[bl * 260 + g4 * 4];
    out4[ ((size_t)s * 128 + kh * 64 + g4) * 64 + bh * 32 + bl ] = v;
  }
}

// ---------------- KW: split W_hh (both dirs) into bf16 hi|lo: WBS[d][2048 rows][1024 ccat] ----------------
__global__ void __launch_bounds__(256) kw_split(const float* __restrict__ Whh_f,
    const float* __restrict__ Whh_b, ushort* __restrict__ WBS) {
  int idx = blockIdx.x * 256 + threadIdx.x;   // [0, 524288): d(1) x row(2048) x k4(128)
  int d = idx >> 18;
  int r = (idx >> 7) & 2047;
  int k4 = idx & 127;
  const float* W = d ? Whh_b : Whh_f;
  float4 v = *(const float4*)&W[(size_t)r * 512 + k4 * 4];
  ushort h0 = bf16_rne(v.x), h1 = bf16_rne(v.y), h2 = bf16_rne(v.z), h3 = bf16_rne(v.w);
  ushort l0 = bf16_rne(v.x - bf16_tof(h0));
  ushort l1 = bf16_rne(v.y - bf16_tof(h1));
  ushort l2 = bf16_rne(v.z - bf16_tof(h2));
  ushort l3 = bf16_rne(v.w - bf16_tof(h3));
  ushort* base = WBS + (size_t)d * 2048 * 1024 + (size_t)r * 1024;
  uint2 HI = { (uint)h0 | ((uint)h1 << 16), (uint)h2 | ((uint)h3 << 16) };
  uint2 LO = { (uint)l0 | ((uint)l1 << 16), (uint)l2 | ((uint)l3 << 16) };
  *(uint2*)(base + k4 * 4) = HI;
  *(uint2*)(base + 512 + k4 * 4) = LO;
}

// ---------------- K1: xg chunk producer. XG[d][tl][2048 rows][64 b] ----------------
__global__ void __launch_bounds__(256) k1_xg(const float* __restrict__ XT4,
    const float* __restrict__ Wih_f, const float* __restrict__ Wih_b,
    const float* __restrict__ bih_f, const float* __restrict__ bhh_f,
    const float* __restrict__ bih_b, const float* __restrict__ bhh_b,
    float* __restrict__ XG, int c0) {
  __shared__ float4 wlds4[2048];            // 16 rows x 128 f4 = 32 KB
  int wg = blockIdx.x;
  int d  = wg & 1;
  int gs = (wg >> 1) & 127;
  int s8 = wg >> 8;                         // [0,4)
  int tid = threadIdx.x;
  int wid = RFL((int)(tid >> 6));
  int b = tid & 63;
  int tl0 = s8 * 8 + wid * 2;
  int t0 = c0 + tl0;
  int pos0 = d ? (511 - t0) : t0;
  int pos1 = d ? (511 - (t0 + 1)) : (t0 + 1);
  const float* Wih = d ? Wih_b : Wih_f;
  const float* bih = d ? bih_b : bih_f;
  const float* bhh = d ? bhh_b : bhh_f;
  const float* __restrict__ W0 = Wih + (size_t)gs * 16 * 512;
#pragma unroll
  for (int i = 0; i < 8; ++i) {
    int q = i * 256 + tid;
    wlds4[q] = *(const float4*)&W0[(size_t)(q >> 7) * 512 + (size_t)(q & 127) * 4];
  }
  float acc0[16], acc1[16];
#pragma unroll
  for (int r = 0; r < 16; ++r) {
    float bb = bih[gs * 16 + r] + bhh[gs * 16 + r];
    acc0[r] = bb; acc1[r] = bb;
  }
  __syncthreads();
  const float4* X4 = (const float4*)XT4;
  for (int kc = 0; kc < 512; kc += 4) {
    float4 x0 = X4[((size_t)pos0 * 128 + (kc >> 2)) * 64 + b];
    float4 x1 = X4[((size_t)pos1 * 128 + (kc >> 2)) * 64 + b];
#pragma unroll
    for (int r = 0; r < 16; ++r) {
      float4 wv = wlds4[r * 128 + (kc >> 2)];
      acc0[r] = fmaf(wv.x, x0.x, acc0[r]); acc0[r] = fmaf(wv.y, x0.y, acc0[r]);
      acc0[r] = fmaf(wv.z, x0.z, acc0[r]); acc0[r] = fmaf(wv.w, x0.w, acc0[r]);
      acc1[r] = fmaf(wv.x, x1.x, acc1[r]); acc1[r] = fmaf(wv.y, x1.y, acc1[r]);
      acc1[r] = fmaf(wv.z, x1.z, acc1[r]); acc1[r] = fmaf(wv.w, x1.w, acc1[r]);
    }
  }
#pragma unroll
  for (int r = 0; r < 16; ++r) {
    XG[((size_t)(d * 32 + tl0)     * 2048 + gs * 16 + r) * 64 + b] = acc0[r];
    XG[((size_t)(d * 32 + tl0 + 1) * 2048 + gs * 16 + r) * 64 + b] = acc1[r];
  }
}

// ---------------- K2: cooperative recurrence, MFMA split-bf16, 32 steps per launch ----------------
// 64 blocks: d = bid&1, jt = bid>>1 (32 j-tiles of 16 per dir). 512 threads = 8 waves = k-eighths.
// Wave kq owns ccat-slices c32 in {2kq, 2kq+1, 16+2kq, 16+2kq+1} (hi/lo paired, 2-pass cross terms).
// A (W split) persistent in VGPRs; B (h split) loaded DIRECTLY from global HTB (pre-split bf16,
// fragment-native layout [parity][dir][ccat-slice32][b64][32]). LDS = part only (160 KB).
// Single-level per-dir barrier (monotonic counter in Bar).
__global__ void __launch_bounds__(512, 1) k2_rnn(const ushort* __restrict__ WBS,
    const float* __restrict__ XG, ushort* __restrict__ HTB, float* __restrict__ OUTT,
    float* __restrict__ Cws, unsigned int* __restrict__ Bar, int c0) {
  extern __shared__ float part[];               // [kq8][g4][b64][20] f32 = 160 KB
  int bid = blockIdx.x;
  int d = bid & 1, jt = bid >> 1;
  int tid = threadIdx.x;
  int kq = RFL((int)(tid >> 6));
  int lane = tid & 63;
  int l15 = lane & 15, l4 = lane >> 4;

  const int c32s[4] = { 2*kq, 2*kq + 1, 16 + 2*kq, 16 + 2*kq + 1 };

  // A-frag preload (once per dispatch): lane l: row g*512 + jt*16 + l15, c = c32*32 + 8*l4
  bf16x8 Afr[4][4];
  const ushort* WB = WBS + (size_t)d * 2048 * 1024;
#pragma unroll
  for (int g = 0; g < 4; ++g)
#pragma unroll
    for (int s = 0; s < 4; ++s) {
      int row = g * 512 + jt * 16 + l15;
      int c = c32s[s] * 32 + 8 * l4;
      Afr[g][s] = *(const bf16x8*)(WB + (size_t)row * 1024 + c);
    }

  // gate-thread mapping: (jj = tid&15, b = tid>>4 in [0,32)) handles b and b+32
  int jj_g = tid & 15, b_g = tid >> 4;
  int j_g = jt * 16 + jj_g;
  float c_a = Cws[(size_t)(d * 512 + j_g) * 64 + b_g];
  float c_b = Cws[(size_t)(d * 512 + j_g) * 64 + b_g + 32];

  unsigned int* rootc = Bar + d * 32;           // 128 B apart per dir

  for (int tl = 0; tl < 32; ++tl) {
    int t = c0 + tl, p = t & 1;
    // ---- B-frag load direct from global (h pre-split bf16, frag-native layout)
    const ushort* hb = HTB + (size_t)(p * 2 + d) * 65536;
    bf16x8 Bfr[4][4];
#pragma unroll
    for (int bt = 0; bt < 4; ++bt)
#pragma unroll
      for (int s = 0; s < 4; ++s)
        Bfr[bt][s] = *(const bf16x8*)(hb + (size_t)c32s[s] * 2048 + (bt * 16 + l15) * 32 + 8 * l4);
    // ---- gate-bias prefetch (independent)
    float xg[4][2];
    {
      size_t xb = (size_t)(d * 32 + tl) * 2048;
#pragma unroll
      for (int g = 0; g < 4; ++g) {
        xg[g][0] = XG[(xb + g * 512 + j_g) * 64 + b_g];
        xg[g][1] = XG[(xb + g * 512 + j_g) * 64 + b_g + 32];
      }
    }
    // ---- MFMA: 2 passes (main: A[s]xB[s]; cross: A[s]xB[s^2])
    f32x4 acc[4][4];
#pragma unroll
    for (int g = 0; g < 4; ++g)
#pragma unroll
      for (int bt = 0; bt < 4; ++bt) acc[g][bt] = (f32x4){0.f, 0.f, 0.f, 0.f};
#pragma unroll
    for (int pass = 0; pass < 2; ++pass) {
#pragma unroll
      for (int s = 0; s < 4; ++s) {
        int bs = pass ? (s ^ 2) : s;
#pragma unroll
        for (int g = 0; g < 4; ++g)
#pragma unroll
          for (int bt = 0; bt < 4; ++bt)
            acc[g][bt] = __builtin_amdgcn_mfma_f32_16x16x32_bf16(
                Afr[g][s], Bfr[bt][bs], acc[g][bt], 0, 0, 0);
      }
    }
    // ---- part write: [kq][g][b][20], j = 4*l4 + reg
#pragma unroll
    for (int g = 0; g < 4; ++g)
#pragma unroll
      for (int bt = 0; bt < 4; ++bt) {
        int w = ((kq * 4 + g) * 64 + bt * 16 + l15) * 20 + 4 * l4;
        *(f32x4*)&part[w] = acc[g][bt];
      }
    __syncthreads();
    // ---- gate phase: all 512 threads, 2 units each
    int pos = d ? (511 - t) : t;
    ushort* hbn = HTB + (size_t)((p ^ 1) * 2 + d) * 65536;
#pragma unroll
    for (int u = 0; u < 2; ++u) {
      int b = b_g + 32 * u;
      float pre[4];
#pragma unroll
      for (int g = 0; g < 4; ++g) {
        float acc_s = xg[g][u];
#pragma unroll
        for (int kqi = 0; kqi < 8; ++kqi)
          acc_s += part[((kqi * 4 + g) * 64 + b) * 20 + jj_g];
        pre[g] = acc_s;
      }
      float ig = sigm(pre[0]), fg = sigm(pre[1]), gg = tanhf(pre[2]), og = sigm(pre[3]);
      float& cc = u ? c_b : c_a;
      cc = fmaf(fg, cc, ig * gg);
      float h = og * tanhf(cc);
      OUTT[((size_t)(d * 512 + pos) * 512 + j_g) * 64 + b] = h;
      ushort hh = bf16_rne(h);
      ushort hl = bf16_rne(h - bf16_tof(hh));
      hbn[(size_t)(j_g >> 5) * 2048 + b * 32 + (j_g & 31)] = hh;
      hbn[(size_t)(16 + (j_g >> 5)) * 2048 + b * 32 + (j_g & 31)] = hl;
    }
    __syncthreads();   // all waves' stores drained (vmcnt(0) before barrier)
    if (tid == 0) {
      __threadfence(); // release
      unsigned int step1 = (unsigned int)(t + 1);
      atomicAdd(rootc, 1u);
      while (__hip_atomic_load(rootc, __ATOMIC_RELAXED, __HIP_MEMORY_SCOPE_AGENT) < 32u * step1) {
        __builtin_amdgcn_s_sleep(1);
      }
      __threadfence(); // acquire
    }
    __syncthreads();
  }
  Cws[(size_t)(d * 512 + j_g) * 64 + b_g] = c_a;
  Cws[(size_t)(d * 512 + j_g) * 64 + b_g + 32] = c_b;
}

// ---------------- K3a: last-row masked scores ST[t][b] ----------------
__global__ void __launch_bounds__(256) k3a_scores(const float* __restrict__ OUTT, float* __restrict__ ST) {
  int wid = RFL((int)(threadIdx.x >> 6));
  int b = threadIdx.x & 63;
  int t = blockIdx.x * 4 + wid;
  float acc = 0.f;
  for (int dd = 0; dd < 2; ++dd) {
    size_t bt = (size_t)(dd * 512 + t)   * 512;
    size_t bl = (size_t)(dd * 512 + 511) * 512;
    for (int jj = 0; jj < 512; ++jj)
      acc = fmaf(OUTT[(bt + jj) * 64 + b], OUTT[(bl + jj) * 64 + b], acc);
  }
  float sc = acc * (1.0f / 32.0f);
  ST[t * 64 + b] = (sc > 0.1f) ? sc : -1000000.0f;
}

// ---------------- K3b: softmax over t per batch ----------------
__global__ void __launch_bounds__(64) k3b_softmax(const float* __restrict__ ST, float* __restrict__ WT) {
  int b = threadIdx.x;
  float mx = -3.0e38f;
  for (int t = 0; t < 512; ++t) mx = fmaxf(mx, ST[t * 64 + b]);
  float sum = 0.f;
  for (int t = 0; t < 512; ++t) sum += __expf(ST[t * 64 + b] - mx);
  float inv = 1.0f / sum;
  for (int t = 0; t < 512; ++t) WT[t * 64 + b] = __expf(ST[t * 64 + b] - mx) * inv;
}

// ---------------- K3c: context CTX[d*512+j][b] ----------------
__global__ void __launch_bounds__(256) k3c_ctx(const float* __restrict__ OUTT,
    const float* __restrict__ WT, float* __restrict__ CTX) {
  int bq = blockIdx.x;
  int d = bq >> 7, j0 = (bq & 127) * 4;
  int wid = RFL((int)(threadIdx.x >> 6));
  int b = threadIdx.x & 63;
  int j = j0 + wid;
  float acc = 0.f;
  for (int t = 0; t < 512; ++t)
    acc = fmaf(WT[t * 64 + b], OUTT[((size_t)(d * 512 + t) * 512 + j) * 64 + b], acc);
  CTX[(size_t)(d * 512 + j) * 64 + b] = acc;
}

// ---------------- K3d-pre: transpose W_out[256][1024] -> WoT[1024][256] ----------------
__global__ void __launch_bounds__(256) k3dpre(const float* __restrict__ Wout, float* __restrict__ WoT) {
  int o = threadIdx.x;
  int k0 = blockIdx.x * 64;
  for (int k = k0; k < k0 + 64; ++k)
    WoT[k * 256 + o] = Wout[(size_t)o * 1024 + k];
}

// ---------------- K3d: y[b][o] = ctx[b] . WoT[:,o] + b_out[o] ----------------
__global__ void __launch_bounds__(256) k3d_y(const float* __restrict__ CTX,
    const float* __restrict__ WoT, const float* __restrict__ bout, float* __restrict__ y) {
  __shared__ float lc[1024];
  int b = blockIdx.x, o = threadIdx.x;
  for (int k = threadIdx.x; k < 1024; k += 256) lc[k] = CTX[(size_t)k * 64 + b];
  __syncthreads();
  float acc = bout[o];
  for (int k = 0; k < 1024; ++k) acc = fmaf(lc[k], WoT[k * 256 + o], acc);
  y[b * 256 + o] = acc;
}

extern "C" void kernel_launch(void* const* d_in, const int* in_sizes, int n_in,
                              void* d_out, int out_size, void* d_ws, size_t ws_size,
                              hipStream_t stream) {
  (void)in_sizes; (void)n_in; (void)out_size; (void)ws_size;
  const float* inputs = (const float*)d_in[0];
  const float* Wih_f = (const float*)d_in[1];
  const float* Whh_f = (const float*)d_in[2];
  const float* bih_f = (const float*)d_in[3];
  const float* bhh_f = (const float*)d_in[4];
  const float* Wih_b = (const float*)d_in[5];
  const float* Whh_b = (const float*)d_in[6];
  const float* bih_b = (const float*)d_in[7];
  const float* bhh_b = (const float*)d_in[8];
  const float* Wout  = (const float*)d_in[9];
  const float* bout  = (const float*)d_in[10];
  float* y = (float*)d_out;

  float* ws = (float*)d_ws;
  size_t off = 0;
  float* XT4 = ws + off; off += (size_t)512 * 512 * 64;
  float* XG  = ws + off; off += (size_t)2 * 32 * 2048 * 64;
  float* OUTT= ws + off; off += (size_t)2 * 512 * 512 * 64;
  ushort* HTB = (ushort*)(ws + off); off += (size_t)2 * 2 * 64 * 512;  // 512 KB (4x65536 ushort)
  float* Cws = ws + off; off += (size_t)2 * 512 * 64;
  float* ST  = ws + off; off += (size_t)512 * 64;
  float* WT  = ws + off; off += (size_t)512 * 64;
  float* CTX = ws + off; off += (size_t)2 * 512 * 64;
  float* WoT = ws + off; off += (size_t)1024 * 256;
  ushort* WBS = (ushort*)(ws + off); off += (size_t)2 * 2048 * 1024 / 2;  // 4M ushort
  unsigned int* Bar = (unsigned int*)(ws + off); off += 1024;

  hipMemsetAsync(HTB, 0, (size_t)4 * 65536 * sizeof(ushort), stream);
  hipMemsetAsync(Cws, 0, (size_t)2 * 512 * 64 * sizeof(float), stream);
  hipMemsetAsync(Bar, 0, 4096, stream);

  const int ldsK2 = 8 * 4 * 64 * 20 * 4;   // 163,840 B = 160 KB exactly
  hipFuncSetAttribute(reinterpret_cast<const void*>(k2_rnn),
                      hipFuncAttributeMaxDynamicSharedMemorySize, ldsK2);

  k0_transpose<<<2048, 256, 0, stream>>>(inputs, XT4);
  kw_split<<<2048, 256, 0, stream>>>(Whh_f, Whh_b, WBS);

  for (int c = 0; c < 16; ++c) {
    int c0 = c * 32;
    k1_xg<<<1024, 256, 0, stream>>>(XT4, Wih_f, Wih_b, bih_f, bhh_f, bih_b, bhh_b, XG, c0);
    void* args[] = { (void*)&WBS, (void*)&XG, (void*)&HTB,
                     (void*)&OUTT, (void*)&Cws, (void*)&Bar, (void*)&c0 };
    hipLaunchCooperativeKernel(reinterpret_cast<void*>(k2_rnn),
                               dim3(64), dim3(512), args, ldsK2, stream);
  }

  k3a_scores<<<128, 256, 0, stream>>>(OUTT, ST);
  k3b_softmax<<<1, 64, 0, stream>>>(ST, WT);
  k3c_ctx<<<256, 256, 0, stream>>>(OUTT, WT, CTX);
  k3dpre<<<16, 256, 0, stream>>>(Wout, WoT);
  k3d_y<<<64, 256, 0, stream>>>(CTX, WoT, bout, y);
}

// Round 8
// 7290.215 us; speedup vs baseline: 3.5179x; 1.0824x over previous
//
#include <hip/hip_runtime.h>
#include <hip/hip_cooperative_groups.h>
#include <hip/hip_bf16.h>

#define RFL(x) __builtin_amdgcn_readfirstlane(x)

typedef __attribute__((ext_vector_type(8))) short bf16x8;
typedef __attribute__((ext_vector_type(4))) float f32x4;

__device__ __forceinline__ float sigm(float x) { return 1.0f / (1.0f + __expf(-x)); }

__device__ __forceinline__ ushort bf16_rne(float x) {
  __hip_bfloat16 h = __float2bfloat16(x);
  return *reinterpret_cast<ushort*>(&h);
}
__device__ __forceinline__ float bf16_tof(ushort u) {
  __hip_bfloat16 h = *reinterpret_cast<__hip_bfloat16*>(&u);
  return __bfloat162float(h);
}

// agent-scope (MALL-coherent) helpers: bypass L1/L2 so the per-step acquire-invalidate
// doesn't force HBM refetch of these buffers. Used WITH the proven fence protocol.
__device__ __forceinline__ unsigned long long ld_agent_u64(const void* p) {
  return __hip_atomic_load((unsigned long long*)p, __ATOMIC_RELAXED, __HIP_MEMORY_SCOPE_AGENT);
}
__device__ __forceinline__ float ld_agent_f32(const float* p) {
  return __hip_atomic_load(p, __ATOMIC_RELAXED, __HIP_MEMORY_SCOPE_AGENT);
}
__device__ __forceinline__ void st_agent_u16(ushort* p, ushort v) {
  __hip_atomic_store(p, v, __ATOMIC_RELAXED, __HIP_MEMORY_SCOPE_AGENT);
}

// ---------------- KW: split Whh_f, Whh_b, Wih_f, Wih_b -> bf16 hi|lo WBS[m][2048][1024] ----------------
__global__ void __launch_bounds__(256) kw_split2(const float* __restrict__ Whh_f,
    const float* __restrict__ Whh_b, const float* __restrict__ Wih_f,
    const float* __restrict__ Wih_b, ushort* __restrict__ WBS) {
  int idx = blockIdx.x * 256 + threadIdx.x;   // [0, 1048576): m(2b) x row(2048) x k4(128)
  int m = idx >> 18;
  int r = (idx >> 7) & 2047;
  int k4 = idx & 127;
  const float* W = (m == 0) ? Whh_f : (m == 1) ? Whh_b : (m == 2) ? Wih_f : Wih_b;
  float4 v = *(const float4*)&W[(size_t)r * 512 + k4 * 4];
  ushort h0 = bf16_rne(v.x), h1 = bf16_rne(v.y), h2 = bf16_rne(v.z), h3 = bf16_rne(v.w);
  ushort l0 = bf16_rne(v.x - bf16_tof(h0));
  ushort l1 = bf16_rne(v.y - bf16_tof(h1));
  ushort l2 = bf16_rne(v.z - bf16_tof(h2));
  ushort l3 = bf16_rne(v.w - bf16_tof(h3));
  ushort* base = WBS + (size_t)m * 2048 * 1024 + (size_t)r * 1024;
  uint2 HI = { (uint)h0 | ((uint)h1 << 16), (uint)h2 | ((uint)h3 << 16) };
  uint2 LO = { (uint)l0 | ((uint)l1 << 16), (uint)l2 | ((uint)l3 << 16) };
  *(uint2*)(base + k4 * 4) = HI;
  *(uint2*)(base + 512 + k4 * 4) = LO;
}

// ---------------- KX: inputs (B,S,512) -> split bf16 B-frag-native XBS[s][c32 32][b 64][32] ----------------
__global__ void __launch_bounds__(256) kx_split(const float* __restrict__ in, ushort* __restrict__ XBS) {
  int idx = blockIdx.x * 256 + threadIdx.x;   // b(6) | k8(6) | s(9)
  int b = idx & 63;
  int k8 = (idx >> 6) & 63;
  int s = idx >> 12;
  const float* ip = in + ((size_t)b * 512 + s) * 512 + k8 * 8;
  float4 v0 = *(const float4*)ip;
  float4 v1 = *(const float4*)(ip + 4);
  float hv[8] = { v0.x, v0.y, v0.z, v0.w, v1.x, v1.y, v1.z, v1.w };
  ushort hi[8], lo[8];
#pragma unroll
  for (int e = 0; e < 8; ++e) {
    hi[e] = bf16_rne(hv[e]);
    lo[e] = bf16_rne(hv[e] - bf16_tof(hi[e]));
  }
  uint4 HI = { (uint)hi[0] | ((uint)hi[1] << 16), (uint)hi[2] | ((uint)hi[3] << 16),
               (uint)hi[4] | ((uint)hi[5] << 16), (uint)hi[6] | ((uint)hi[7] << 16) };
  uint4 LO = { (uint)lo[0] | ((uint)lo[1] << 16), (uint)lo[2] | ((uint)lo[3] << 16),
               (uint)lo[4] | ((uint)lo[5] << 16), (uint)lo[6] | ((uint)lo[7] << 16) };
  int c32 = k8 >> 2;
  ushort* xs = XBS + (size_t)s * 65536 + b * 32 + (k8 & 3) * 8;
  *(uint4*)(xs + (size_t)c32 * 2048) = HI;
  *(uint4*)(xs + (size_t)(16 + c32) * 2048) = LO;
}

// ---------------- K1: xg producer via MFMA split-bf16. XG[d][tl 32][2048 rows][64 b] ----------------
// 256 blocks: jt = bid&31 (16 j), d = (bid>>5)&1, ts = bid>>6 (8 steps each). 8 waves = k-eighths.
// No inter-block sync. Wih frags persistent in VGPRs; B-frags from XBS (cached path).
__global__ void __launch_bounds__(512, 1) k1_xg(const ushort* __restrict__ WBS,
    const ushort* __restrict__ XBS,
    const float* __restrict__ bih_f, const float* __restrict__ bhh_f,
    const float* __restrict__ bih_b, const float* __restrict__ bhh_b,
    float* __restrict__ XG, int c0) {
  extern __shared__ float part[];               // [kq8][g4][b64][20] f32 = 160 KB
  int bid = blockIdx.x;
  int jt = bid & 31;
  int d  = (bid >> 5) & 1;
  int ts = bid >> 6;                            // [0,4): handles tl = ts*8 .. ts*8+7
  int tid = threadIdx.x;
  int kq = RFL((int)(tid >> 6));
  int lane = tid & 63;
  int l15 = lane & 15, l4 = lane >> 4;
  const int c32s[4] = { 2*kq, 2*kq + 1, 16 + 2*kq, 16 + 2*kq + 1 };

  bf16x8 Afr[4][4];
  const ushort* WB = WBS + (size_t)(2 + d) * 2048 * 1024;     // Wih_f at m=2, Wih_b at m=3
#pragma unroll
  for (int g = 0; g < 4; ++g)
#pragma unroll
    for (int s = 0; s < 4; ++s)
      Afr[g][s] = *(const bf16x8*)(WB + (size_t)(g * 512 + jt * 16 + l15) * 1024 + c32s[s] * 32 + 8 * l4);

  int jj_g = tid & 15, b_g = tid >> 4;          // b_g in [0,32)
  int j_g = jt * 16 + jj_g;
  const float* bih = d ? bih_b : bih_f;
  const float* bhh = d ? bhh_b : bhh_f;
  float bias[4];
#pragma unroll
  for (int g = 0; g < 4; ++g) bias[g] = bih[g * 512 + j_g] + bhh[g * 512 + j_g];

#pragma unroll 1
  for (int tl = ts * 8; tl < ts * 8 + 8; ++tl) {
    int t = c0 + tl;
    int pos = d ? (511 - t) : t;
    const ushort* xb = XBS + (size_t)pos * 65536;
    bf16x8 Bfr[4][4];
#pragma unroll
    for (int bt = 0; bt < 4; ++bt)
#pragma unroll
      for (int s = 0; s < 4; ++s)
        Bfr[bt][s] = *(const bf16x8*)(xb + (size_t)c32s[s] * 2048 + (bt * 16 + l15) * 32 + 8 * l4);
    f32x4 acc[4][4];
#pragma unroll
    for (int g = 0; g < 4; ++g)
#pragma unroll
      for (int bt = 0; bt < 4; ++bt) acc[g][bt] = (f32x4){0.f, 0.f, 0.f, 0.f};
#pragma unroll
    for (int pass = 0; pass < 2; ++pass) {
#pragma unroll
      for (int s = 0; s < 4; ++s) {
        int bs = pass ? (s ^ 2) : s;
#pragma unroll
        for (int g = 0; g < 4; ++g)
#pragma unroll
          for (int bt = 0; bt < 4; ++bt)
            acc[g][bt] = __builtin_amdgcn_mfma_f32_16x16x32_bf16(
                Afr[g][s], Bfr[bt][bs], acc[g][bt], 0, 0, 0);
      }
    }
    __syncthreads();     // previous iteration's part reads are done
#pragma unroll
    for (int g = 0; g < 4; ++g)
#pragma unroll
      for (int bt = 0; bt < 4; ++bt) {
        int w = ((kq * 4 + g) * 64 + bt * 16 + l15) * 20 + 4 * l4;
        *(f32x4*)&part[w] = acc[g][bt];
      }
    __syncthreads();
    size_t xgb = (size_t)(d * 32 + tl) * 2048;
#pragma unroll
    for (int u = 0; u < 2; ++u) {
      int b = b_g + 32 * u;
#pragma unroll
      for (int g = 0; g < 4; ++g) {
        float pre = bias[g];
#pragma unroll
        for (int kqi = 0; kqi < 8; ++kqi)
          pre += part[((kqi * 4 + g) * 64 + b) * 20 + jj_g];
        XG[(xgb + g * 512 + j_g) * 64 + b] = pre;
      }
    }
  }
}

// ---------------- K2: cooperative recurrence, MFMA split-bf16, 32 steps per launch ----------------
// R5-PROVEN protocol: __threadfence release/acquire around a per-dir monotonic barrier
// (+ bounded spin guard). XG reads and HTB h-exchange use agent-scope (MALL) ops so the
// acquire-invalidate doesn't trigger HBM refetch. A frags persistent in VGPRs; LDS = part only.
__global__ void __launch_bounds__(512, 1) k2_rnn(const ushort* __restrict__ WBS,
    const float* __restrict__ XG, ushort* __restrict__ HTB, float* __restrict__ OUTT,
    float* __restrict__ Cws, unsigned int* __restrict__ Bar, int c0) {
  extern __shared__ float part[];               // [kq8][g4][b64][20] f32 = 160 KB
  int bid = blockIdx.x;
  int d = bid & 1, jt = bid >> 1;
  int tid = threadIdx.x;
  int kq = RFL((int)(tid >> 6));
  int lane = tid & 63;
  int l15 = lane & 15, l4 = lane >> 4;

  const int c32s[4] = { 2*kq, 2*kq + 1, 16 + 2*kq, 16 + 2*kq + 1 };

  bf16x8 Afr[4][4];
  const ushort* WB = WBS + (size_t)d * 2048 * 1024;
#pragma unroll
  for (int g = 0; g < 4; ++g)
#pragma unroll
    for (int s = 0; s < 4; ++s) {
      int row = g * 512 + jt * 16 + l15;
      int c = c32s[s] * 32 + 8 * l4;
      Afr[g][s] = *(const bf16x8*)(WB + (size_t)row * 1024 + c);
    }

  int jj_g = tid & 15, b_g = tid >> 4;
  int j_g = jt * 16 + jj_g;
  float c_a = Cws[(size_t)(d * 512 + j_g) * 64 + b_g];
  float c_b = Cws[(size_t)(d * 512 + j_g) * 64 + b_g + 32];

  unsigned int* rootc = Bar + d * 32;           // 128 B apart per dir

  for (int tl = 0; tl < 32; ++tl) {
    int t = c0 + tl, p = t & 1;
    // ---- B-frag load via agent-scope (MALL) u64 pairs
    const ushort* hb = HTB + (size_t)(p * 2 + d) * 65536;
    bf16x8 Bfr[4][4];
#pragma unroll
    for (int bt = 0; bt < 4; ++bt)
#pragma unroll
      for (int s = 0; s < 4; ++s) {
        const ushort* fp = hb + (size_t)c32s[s] * 2048 + (bt * 16 + l15) * 32 + 8 * l4;
        union { bf16x8 v; unsigned long long q[2]; } u;
        u.q[0] = ld_agent_u64(fp);
        u.q[1] = ld_agent_u64(fp + 4);
        Bfr[bt][s] = u.v;
      }
    // ---- gate-bias prefetch via agent loads (MALL-resident; immune to L2 invalidate)
    float xg[4][2];
    {
      size_t xb = (size_t)(d * 32 + tl) * 2048;
#pragma unroll
      for (int g = 0; g < 4; ++g) {
        xg[g][0] = ld_agent_f32(&XG[(xb + g * 512 + j_g) * 64 + b_g]);
        xg[g][1] = ld_agent_f32(&XG[(xb + g * 512 + j_g) * 64 + b_g + 32]);
      }
    }
    // ---- MFMA: 2 passes (main: A[s]xB[s]; cross: A[s]xB[s^2])
    f32x4 acc[4][4];
#pragma unroll
    for (int g = 0; g < 4; ++g)
#pragma unroll
      for (int bt = 0; bt < 4; ++bt) acc[g][bt] = (f32x4){0.f, 0.f, 0.f, 0.f};
#pragma unroll
    for (int pass = 0; pass < 2; ++pass) {
#pragma unroll
      for (int s = 0; s < 4; ++s) {
        int bs = pass ? (s ^ 2) : s;
#pragma unroll
        for (int g = 0; g < 4; ++g)
#pragma unroll
          for (int bt = 0; bt < 4; ++bt)
            acc[g][bt] = __builtin_amdgcn_mfma_f32_16x16x32_bf16(
                Afr[g][s], Bfr[bt][bs], acc[g][bt], 0, 0, 0);
      }
    }
    // ---- part write: [kq][g][b][20], j = 4*l4 + reg
#pragma unroll
    for (int g = 0; g < 4; ++g)
#pragma unroll
      for (int bt = 0; bt < 4; ++bt) {
        int w = ((kq * 4 + g) * 64 + bt * 16 + l15) * 20 + 4 * l4;
        *(f32x4*)&part[w] = acc[g][bt];
      }
    __syncthreads();
    // ---- gate phase: all 512 threads, 2 units each
    int pos = d ? (511 - t) : t;
    ushort* hbn = HTB + (size_t)((p ^ 1) * 2 + d) * 65536;
#pragma unroll
    for (int u = 0; u < 2; ++u) {
      int b = b_g + 32 * u;
      float pre[4];
#pragma unroll
      for (int g = 0; g < 4; ++g) {
        float acc_s = xg[g][u];
#pragma unroll
        for (int kqi = 0; kqi < 8; ++kqi)
          acc_s += part[((kqi * 4 + g) * 64 + b) * 20 + jj_g];
        pre[g] = acc_s;
      }
      float ig = sigm(pre[0]), fg = sigm(pre[1]), gg = tanhf(pre[2]), og = sigm(pre[3]);
      float& cc = u ? c_b : c_a;
      cc = fmaf(fg, cc, ig * gg);
      float h = og * tanhf(cc);
      OUTT[((size_t)(d * 512 + pos) * 512 + j_g) * 64 + b] = h;
      ushort hh = bf16_rne(h);
      ushort hl = bf16_rne(h - bf16_tof(hh));
      st_agent_u16(hbn + (size_t)(j_g >> 5) * 2048 + b * 32 + (j_g & 31), hh);
      st_agent_u16(hbn + (size_t)(16 + (j_g >> 5)) * 2048 + b * 32 + (j_g & 31), hl);
    }
    __syncthreads();   // drains each wave's vmcnt -> block's stores issued
    if (tid == 0) {
      __threadfence(); // release (R5-proven)
      unsigned int step1 = (unsigned int)(t + 1);
      atomicAdd(rootc, 1u);
      int guard = 0;   // bounded spin: pathological stall -> wrong answer, not a GPU wedge
      while (__hip_atomic_load(rootc, __ATOMIC_RELAXED, __HIP_MEMORY_SCOPE_AGENT) < 32u * step1 &&
             ++guard < (1 << 22)) {
        __builtin_amdgcn_s_sleep(1);
      }
      __threadfence(); // acquire (R5-proven)
    }
    __syncthreads();
  }
  Cws[(size_t)(d * 512 + j_g) * 64 + b_g] = c_a;
  Cws[(size_t)(d * 512 + j_g) * 64 + b_g + 32] = c_b;
}

// ---------------- K3a: last-row masked scores ST[t][b] ----------------
__global__ void __launch_bounds__(256) k3a_scores(const float* __restrict__ OUTT, float* __restrict__ ST) {
  int wid = RFL((int)(threadIdx.x >> 6));
  int b = threadIdx.x & 63;
  int t = blockIdx.x * 4 + wid;
  float acc = 0.f;
  for (int dd = 0; dd < 2; ++dd) {
    size_t bt = (size_t)(dd * 512 + t)   * 512;
    size_t bl = (size_t)(dd * 512 + 511) * 512;
    for (int jj = 0; jj < 512; ++jj)
      acc = fmaf(OUTT[(bt + jj) * 64 + b], OUTT[(bl + jj) * 64 + b], acc);
  }
  float sc = acc * (1.0f / 32.0f);
  ST[t * 64 + b] = (sc > 0.1f) ? sc : -1000000.0f;
}

// ---------------- K3b: softmax over t per batch ----------------
__global__ void __launch_bounds__(64) k3b_softmax(const float* __restrict__ ST, float* __restrict__ WT) {
  int b = threadIdx.x;
  float mx = -3.0e38f;
  for (int t = 0; t < 512; ++t) mx = fmaxf(mx, ST[t * 64 + b]);
  float sum = 0.f;
  for (int t = 0; t < 512; ++t) sum += __expf(ST[t * 64 + b] - mx);
  float inv = 1.0f / sum;
  for (int t = 0; t < 512; ++t) WT[t * 64 + b] = __expf(ST[t * 64 + b] - mx) * inv;
}

// ---------------- K3c: context CTX[d*512+j][b] ----------------
__global__ void __launch_bounds__(256) k3c_ctx(const float* __restrict__ OUTT,
    const float* __restrict__ WT, float* __restrict__ CTX) {
  int bq = blockIdx.x;
  int d = bq >> 7, j0 = (bq & 127) * 4;
  int wid = RFL((int)(threadIdx.x >> 6));
  int b = threadIdx.x & 63;
  int j = j0 + wid;
  float acc = 0.f;
  for (int t = 0; t < 512; ++t)
    acc = fmaf(WT[t * 64 + b], OUTT[((size_t)(d * 512 + t) * 512 + j) * 64 + b], acc);
  CTX[(size_t)(d * 512 + j) * 64 + b] = acc;
}

// ---------------- K3d-pre: transpose W_out[256][1024] -> WoT[1024][256] ----------------
__global__ void __launch_bounds__(256) k3dpre(const float* __restrict__ Wout, float* __restrict__ WoT) {
  int o = threadIdx.x;
  int k0 = blockIdx.x * 64;
  for (int k = k0; k < k0 + 64; ++k)
    WoT[k * 256 + o] = Wout[(size_t)o * 1024 + k];
}

// ---------------- K3d: y[b][o] = ctx[b] . WoT[:,o] + b_out[o] ----------------
__global__ void __launch_bounds__(256) k3d_y(const float* __restrict__ CTX,
    const float* __restrict__ WoT, const float* __restrict__ bout, float* __restrict__ y) {
  __shared__ float lc[1024];
  int b = blockIdx.x, o = threadIdx.x;
  for (int k = threadIdx.x; k < 1024; k += 256) lc[k] = CTX[(size_t)k * 64 + b];
  __syncthreads();
  float acc = bout[o];
  for (int k = 0; k < 1024; ++k) acc = fmaf(lc[k], WoT[k * 256 + o], acc);
  y[b * 256 + o] = acc;
}

extern "C" void kernel_launch(void* const* d_in, const int* in_sizes, int n_in,
                              void* d_out, int out_size, void* d_ws, size_t ws_size,
                              hipStream_t stream) {
  (void)in_sizes; (void)n_in; (void)out_size; (void)ws_size;
  const float* inputs = (const float*)d_in[0];
  const float* Wih_f = (const float*)d_in[1];
  const float* Whh_f = (const float*)d_in[2];
  const float* bih_f = (const float*)d_in[3];
  const float* bhh_f = (const float*)d_in[4];
  const float* Wih_b = (const float*)d_in[5];
  const float* Whh_b = (const float*)d_in[6];
  const float* bih_b = (const float*)d_in[7];
  const float* bhh_b = (const float*)d_in[8];
  const float* Wout  = (const float*)d_in[9];
  const float* bout  = (const float*)d_in[10];
  float* y = (float*)d_out;

  float* ws = (float*)d_ws;
  size_t off = 0;
  ushort* XBS = (ushort*)(ws + off); off += (size_t)512 * 32 * 64 * 32 / 2;   // 64 MB
  float* XG  = ws + off; off += (size_t)2 * 32 * 2048 * 64;                    // 32 MB
  float* OUTT= ws + off; off += (size_t)2 * 512 * 512 * 64;                    // 128 MB
  ushort* HTB = (ushort*)(ws + off); off += (size_t)2 * 2 * 64 * 512;          // 512 KB
  float* Cws = ws + off; off += (size_t)2 * 512 * 64;
  float* ST  = ws + off; off += (size_t)512 * 64;
  float* WT  = ws + off; off += (size_t)512 * 64;
  float* CTX = ws + off; off += (size_t)2 * 512 * 64;
  float* WoT = ws + off; off += (size_t)1024 * 256;
  ushort* WBS = (ushort*)(ws + off); off += (size_t)4 * 2048 * 1024 / 2;       // 16 MB
  unsigned int* Bar = (unsigned int*)(ws + off); off += 1024;

  hipMemsetAsync(HTB, 0, (size_t)4 * 65536 * sizeof(ushort), stream);
  hipMemsetAsync(Cws, 0, (size_t)2 * 512 * 64 * sizeof(float), stream);
  hipMemsetAsync(Bar, 0, 4096, stream);

  const int ldsK = 8 * 4 * 64 * 20 * 4;   // 163,840 B = 160 KB exactly
  hipFuncSetAttribute(reinterpret_cast<const void*>(k2_rnn),
                      hipFuncAttributeMaxDynamicSharedMemorySize, ldsK);
  hipFuncSetAttribute(reinterpret_cast<const void*>(k1_xg),
                      hipFuncAttributeMaxDynamicSharedMemorySize, ldsK);

  kw_split2<<<4096, 256, 0, stream>>>(Whh_f, Whh_b, Wih_f, Wih_b, WBS);
  kx_split<<<8192, 256, 0, stream>>>(inputs, XBS);

  for (int c = 0; c < 16; ++c) {
    int c0 = c * 32;
    k1_xg<<<256, 512, ldsK, stream>>>(WBS, XBS, bih_f, bhh_f, bih_b, bhh_b, XG, c0);
    void* args[] = { (void*)&WBS, (void*)&XG, (void*)&HTB,
                     (void*)&OUTT, (void*)&Cws, (void*)&Bar, (void*)&c0 };
    hipLaunchCooperativeKernel(reinterpret_cast<void*>(k2_rnn),
                               dim3(64), dim3(512), args, ldsK, stream);
  }

  k3a_scores<<<128, 256, 0, stream>>>(OUTT, ST);
  k3b_softmax<<<1, 64, 0, stream>>>(ST, WT);
  k3c_ctx<<<256, 256, 0, stream>>>(OUTT, WT, CTX);
  k3dpre<<<16, 256, 0, stream>>>(Wout, WoT);
  k3d_y<<<64, 256, 0, stream>>>(CTX, WoT, bout, y);
}

// Round 9
// 4965.965 us; speedup vs baseline: 5.1644x; 1.4680x over previous
//
#include <hip/hip_runtime.h>
#include <hip/hip_cooperative_groups.h>
#include <hip/hip_bf16.h>

#define RFL(x) __builtin_amdgcn_readfirstlane(x)

typedef __attribute__((ext_vector_type(8))) short bf16x8;
typedef __attribute__((ext_vector_type(4))) float f32x4;

__device__ __forceinline__ float sigm(float x) { return 1.0f / (1.0f + __expf(-x)); }

__device__ __forceinline__ ushort bf16_rne(float x) {
  __hip_bfloat16 h = __float2bfloat16(x);
  return *reinterpret_cast<ushort*>(&h);
}
__device__ __forceinline__ float bf16_tof(ushort u) {
  __hip_bfloat16 h = *reinterpret_cast<__hip_bfloat16*>(&u);
  return __bfloat162float(h);
}

// agent-scope (MALL-coherent) helpers: bypass L1/L2 -> no fences needed for this data path
__device__ __forceinline__ unsigned long long ld_agent_u64(const void* p) {
  return __hip_atomic_load((unsigned long long*)p, __ATOMIC_RELAXED, __HIP_MEMORY_SCOPE_AGENT);
}
__device__ __forceinline__ unsigned int ld_agent_u32(const unsigned int* p) {
  return __hip_atomic_load(p, __ATOMIC_RELAXED, __HIP_MEMORY_SCOPE_AGENT);
}
__device__ __forceinline__ void st_agent_u32(unsigned int* p, unsigned int v) {
  __hip_atomic_store(p, v, __ATOMIC_RELAXED, __HIP_MEMORY_SCOPE_AGENT);
}
__device__ __forceinline__ void st_agent_u16(ushort* p, ushort v) {
  __hip_atomic_store(p, v, __ATOMIC_RELAXED, __HIP_MEMORY_SCOPE_AGENT);
}

// ---------------- KW: split Whh_f, Whh_b, Wih_f, Wih_b -> bf16 hi|lo WBS[m][2048][1024] ----------------
__global__ void __launch_bounds__(256) kw_split2(const float* __restrict__ Whh_f,
    const float* __restrict__ Whh_b, const float* __restrict__ Wih_f,
    const float* __restrict__ Wih_b, ushort* __restrict__ WBS) {
  int idx = blockIdx.x * 256 + threadIdx.x;   // [0, 1048576): m(2b) x row(2048) x k4(128)
  int m = idx >> 18;
  int r = (idx >> 7) & 2047;
  int k4 = idx & 127;
  const float* W = (m == 0) ? Whh_f : (m == 1) ? Whh_b : (m == 2) ? Wih_f : Wih_b;
  float4 v = *(const float4*)&W[(size_t)r * 512 + k4 * 4];
  ushort h0 = bf16_rne(v.x), h1 = bf16_rne(v.y), h2 = bf16_rne(v.z), h3 = bf16_rne(v.w);
  ushort l0 = bf16_rne(v.x - bf16_tof(h0));
  ushort l1 = bf16_rne(v.y - bf16_tof(h1));
  ushort l2 = bf16_rne(v.z - bf16_tof(h2));
  ushort l3 = bf16_rne(v.w - bf16_tof(h3));
  ushort* base = WBS + (size_t)m * 2048 * 1024 + (size_t)r * 1024;
  uint2 HI = { (uint)h0 | ((uint)h1 << 16), (uint)h2 | ((uint)h3 << 16) };
  uint2 LO = { (uint)l0 | ((uint)l1 << 16), (uint)l2 | ((uint)l3 << 16) };
  *(uint2*)(base + k4 * 4) = HI;
  *(uint2*)(base + 512 + k4 * 4) = LO;
}

// ---------------- shared producer: xg for (d, jt), steps [tlb, tle) of chunk cx ----------------
// B-frags built on the fly from `inputs` (split hi/lo); A = Wih frags in VGPRs; part-reduce in LDS.
__device__ __forceinline__ void xg_produce(const ushort* __restrict__ WBS,
    const float* __restrict__ inputs,
    const float* __restrict__ bih_f, const float* __restrict__ bhh_f,
    const float* __restrict__ bih_b, const float* __restrict__ bhh_b,
    float* __restrict__ XGo, float* part,
    int d, int jt, int cx, int tlb, int tle, int tid, int kq, int l15, int l4) {
  bf16x8 Afr[4][4];
  const ushort* WB = WBS + (size_t)(2 + d) * 2048 * 1024;     // Wih_f at m=2, Wih_b at m=3
  const int c32s[4] = { 2*kq, 2*kq + 1, 16 + 2*kq, 16 + 2*kq + 1 };
#pragma unroll
  for (int g = 0; g < 4; ++g)
#pragma unroll
    for (int s = 0; s < 4; ++s)
      Afr[g][s] = *(const bf16x8*)(WB + (size_t)(g * 512 + jt * 16 + l15) * 1024 + c32s[s] * 32 + 8 * l4);

  int jj_g = tid & 15, b_g = tid >> 4;          // b_g in [0,32)
  int j_g = jt * 16 + jj_g;
  const float* bih = d ? bih_b : bih_f;
  const float* bhh = d ? bhh_b : bhh_f;
  float bias[4];
#pragma unroll
  for (int g = 0; g < 4; ++g) bias[g] = bih[g * 512 + j_g] + bhh[g * 512 + j_g];

#pragma unroll 1
  for (int tl = tlb; tl < tle; ++tl) {
    int t = cx + tl;
    int pos = d ? (511 - t) : t;
    // B-frags: slice q (hi) and 2+q (lo) share the k-range (2kq+q)*32 + 8*l4 .. +8
    bf16x8 Bfr[4][4];
#pragma unroll
    for (int bt = 0; bt < 4; ++bt) {
      const float* bp = inputs + ((size_t)(bt * 16 + l15) * 512 + pos) * 512;
#pragma unroll
      for (int q = 0; q < 2; ++q) {
        int k0 = (2 * kq + q) * 32 + 8 * l4;
        float4 x0 = *(const float4*)(bp + k0);
        float4 x1 = *(const float4*)(bp + k0 + 4);
        float xv[8] = { x0.x, x0.y, x0.z, x0.w, x1.x, x1.y, x1.z, x1.w };
        union { bf16x8 v; ushort u[8]; } H, L;
#pragma unroll
        for (int e = 0; e < 8; ++e) {
          ushort hh = bf16_rne(xv[e]);
          H.u[e] = hh;
          L.u[e] = bf16_rne(xv[e] - bf16_tof(hh));
        }
        Bfr[bt][q] = H.v;
        Bfr[bt][2 + q] = L.v;
      }
    }
    f32x4 acc[4][4];
#pragma unroll
    for (int g = 0; g < 4; ++g)
#pragma unroll
      for (int bt = 0; bt < 4; ++bt) acc[g][bt] = (f32x4){0.f, 0.f, 0.f, 0.f};
#pragma unroll
    for (int pass = 0; pass < 2; ++pass) {
#pragma unroll
      for (int s = 0; s < 4; ++s) {
        int bs = pass ? (s ^ 2) : s;
#pragma unroll
        for (int g = 0; g < 4; ++g)
#pragma unroll
          for (int bt = 0; bt < 4; ++bt)
            acc[g][bt] = __builtin_amdgcn_mfma_f32_16x16x32_bf16(
                Afr[g][s], Bfr[bt][bs], acc[g][bt], 0, 0, 0);
      }
    }
    __syncthreads();     // previous iteration's part reads done
#pragma unroll
    for (int g = 0; g < 4; ++g)
#pragma unroll
      for (int bt = 0; bt < 4; ++bt) {
        int w = ((kq * 4 + g) * 64 + bt * 16 + l15) * 20 + 4 * l4;
        *(f32x4*)&part[w] = acc[g][bt];
      }
    __syncthreads();
    size_t xgb = (size_t)(d * 32 + tl) * 2048;
#pragma unroll
    for (int u = 0; u < 2; ++u) {
      int b = b_g + 32 * u;
#pragma unroll
      for (int g = 0; g < 4; ++g) {
        float pre = bias[g];
#pragma unroll
        for (int kqi = 0; kqi < 8; ++kqi)
          pre += part[((kqi * 4 + g) * 64 + b) * 20 + jj_g];
        XGo[(xgb + g * 512 + j_g) * 64 + b] = pre;
      }
    }
  }
}

// ---------------- prologue: xg for chunk 0 (256 blocks, 8 steps each) ----------------
__global__ void __launch_bounds__(512, 1) k1_pro(const ushort* __restrict__ WBS,
    const float* __restrict__ inputs,
    const float* __restrict__ bih_f, const float* __restrict__ bhh_f,
    const float* __restrict__ bih_b, const float* __restrict__ bhh_b,
    float* __restrict__ XGo) {
  extern __shared__ float part[];
  int bid = blockIdx.x;
  int tid = threadIdx.x;
  int kq = RFL((int)(tid >> 6));
  int lane = tid & 63, l15 = lane & 15, l4 = lane >> 4;
  int jt = bid & 31, d = (bid >> 5) & 1, ts = bid >> 6;    // ts in [0,4)
  xg_produce(WBS, inputs, bih_f, bhh_f, bih_b, bhh_b, XGo, part,
             d, jt, 0, ts * 8, ts * 8 + 8, tid, kq, l15, l4);
}

// ---------------- fused cooperative kernel: 256 blocks ----------------
// Blocks 0..63: recurrence for chunk c0 reading xg_r (R8-proven MFMA structure; fence-free
//   slot barrier: each block agent-stores step# to its own padded slot; wave0 lanes poll all
//   32 slots in parallel, __all ballot; h exchange stays on agent-scope write-through path).
// Blocks 64..255: produce xg for chunk c0+32 into xg_w (idle CUs; no sync with consumers).
__global__ void __launch_bounds__(512, 1) k2_fused(const ushort* __restrict__ WBS,
    const float* __restrict__ inputs, const float* __restrict__ xg_r, float* __restrict__ xg_w,
    ushort* __restrict__ HTB, float* __restrict__ OUTT, float* __restrict__ Cws,
    unsigned int* __restrict__ Bar,
    const float* __restrict__ bih_f, const float* __restrict__ bhh_f,
    const float* __restrict__ bih_b, const float* __restrict__ bhh_b, int c0) {
  extern __shared__ float part[];               // [kq8][g4][b64][20] f32 = 160 KB
  int bid = blockIdx.x;
  int tid = threadIdx.x;
  int kq = RFL((int)(tid >> 6));
  int lane = tid & 63;
  int l15 = lane & 15, l4 = lane >> 4;

  if (bid >= 64) {                              // -------- producer path --------
    int nc0 = c0 + 32;
    if (nc0 >= 512) return;
    int pid = bid - 64;
    int jt = pid & 31, d = (pid >> 5) & 1, ts = pid >> 6;  // ts in [0,3)
    int tlb = ts * 11;
    int tle = tlb + 11; if (tle > 32) tle = 32;
    xg_produce(WBS, inputs, bih_f, bhh_f, bih_b, bhh_b, xg_w, part,
               d, jt, nc0, tlb, tle, tid, kq, l15, l4);
    return;
  }

  // -------- consumer (recurrence) path --------
  int d = bid & 1, jt = bid >> 1;
  const int c32s[4] = { 2*kq, 2*kq + 1, 16 + 2*kq, 16 + 2*kq + 1 };

  bf16x8 Afr[4][4];
  const ushort* WB = WBS + (size_t)d * 2048 * 1024;
#pragma unroll
  for (int g = 0; g < 4; ++g)
#pragma unroll
    for (int s = 0; s < 4; ++s) {
      int row = g * 512 + jt * 16 + l15;
      int c = c32s[s] * 32 + 8 * l4;
      Afr[g][s] = *(const bf16x8*)(WB + (size_t)row * 1024 + c);
    }

  int jj_g = tid & 15, b_g = tid >> 4;
  int j_g = jt * 16 + jj_g;
  float c_a = Cws[(size_t)(d * 512 + j_g) * 64 + b_g];
  float c_b = Cws[(size_t)(d * 512 + j_g) * 64 + b_g + 32];

  unsigned int* slots = Bar + (size_t)d * 512;  // 32 slots, 64 B apart

  for (int tl = 0; tl < 32; ++tl) {
    int t = c0 + tl, p = t & 1;
    // ---- B-frag load via agent-scope (MALL) u64 pairs
    const ushort* hb = HTB + (size_t)(p * 2 + d) * 65536;
    bf16x8 Bfr[4][4];
#pragma unroll
    for (int bt = 0; bt < 4; ++bt)
#pragma unroll
      for (int s = 0; s < 4; ++s) {
        const ushort* fp = hb + (size_t)c32s[s] * 2048 + (bt * 16 + l15) * 32 + 8 * l4;
        union { bf16x8 v; unsigned long long q[2]; } u;
        u.q[0] = ld_agent_u64(fp);
        u.q[1] = ld_agent_u64(fp + 4);
        Bfr[bt][s] = u.v;
      }
    // ---- gate-bias prefetch (normal cached loads; XG immutable during this dispatch)
    float xg[4][2];
    {
      size_t xb = (size_t)(d * 32 + tl) * 2048;
#pragma unroll
      for (int g = 0; g < 4; ++g) {
        xg[g][0] = xg_r[(xb + g * 512 + j_g) * 64 + b_g];
        xg[g][1] = xg_r[(xb + g * 512 + j_g) * 64 + b_g + 32];
      }
    }
    // ---- MFMA: 2 passes (main: A[s]xB[s]; cross: A[s]xB[s^2])
    f32x4 acc[4][4];
#pragma unroll
    for (int g = 0; g < 4; ++g)
#pragma unroll
      for (int bt = 0; bt < 4; ++bt) acc[g][bt] = (f32x4){0.f, 0.f, 0.f, 0.f};
#pragma unroll
    for (int pass = 0; pass < 2; ++pass) {
#pragma unroll
      for (int s = 0; s < 4; ++s) {
        int bs = pass ? (s ^ 2) : s;
#pragma unroll
        for (int g = 0; g < 4; ++g)
#pragma unroll
          for (int bt = 0; bt < 4; ++bt)
            acc[g][bt] = __builtin_amdgcn_mfma_f32_16x16x32_bf16(
                Afr[g][s], Bfr[bt][bs], acc[g][bt], 0, 0, 0);
      }
    }
    // ---- part write: [kq][g][b][20], j = 4*l4 + reg
#pragma unroll
    for (int g = 0; g < 4; ++g)
#pragma unroll
      for (int bt = 0; bt < 4; ++bt) {
        int w = ((kq * 4 + g) * 64 + bt * 16 + l15) * 20 + 4 * l4;
        *(f32x4*)&part[w] = acc[g][bt];
      }
    __syncthreads();
    // ---- gate phase: all 512 threads, 2 units each
    int pos = d ? (511 - t) : t;
    ushort* hbn = HTB + (size_t)((p ^ 1) * 2 + d) * 65536;
#pragma unroll
    for (int u = 0; u < 2; ++u) {
      int b = b_g + 32 * u;
      float pre[4];
#pragma unroll
      for (int g = 0; g < 4; ++g) {
        float acc_s = xg[g][u];
#pragma unroll
        for (int kqi = 0; kqi < 8; ++kqi)
          acc_s += part[((kqi * 4 + g) * 64 + b) * 20 + jj_g];
        pre[g] = acc_s;
      }
      float ig = sigm(pre[0]), fg = sigm(pre[1]), gg = tanhf(pre[2]), og = sigm(pre[3]);
      float& cc = u ? c_b : c_a;
      cc = fmaf(fg, cc, ig * gg);
      float h = og * tanhf(cc);
      OUTT[((size_t)(d * 512 + pos) * 512 + j_g) * 64 + b] = h;
      ushort hh = bf16_rne(h);
      ushort hl = bf16_rne(h - bf16_tof(hh));
      st_agent_u16(hbn + (size_t)(j_g >> 5) * 2048 + b * 32 + (j_g & 31), hh);
      st_agent_u16(hbn + (size_t)(16 + (j_g >> 5)) * 2048 + b * 32 + (j_g & 31), hl);
    }
    __syncthreads();   // every wave drains vmcnt -> h stores at MALL (write-through, agent)
    if (tid < 64) {    // wave 0: contention-free slot barrier
      unsigned int step1 = (unsigned int)(t + 1);
      if (tid == 0) st_agent_u32(&slots[jt * 16], step1);
      unsigned int v;
      int g = 0;
      do {
        v = ld_agent_u32(&slots[(tid & 31) * 16]);
      } while (!__all(v >= step1) && ++g < (1 << 14));
    }
    __syncthreads();
  }
  Cws[(size_t)(d * 512 + j_g) * 64 + b_g] = c_a;
  Cws[(size_t)(d * 512 + j_g) * 64 + b_g + 32] = c_b;
}

// ---------------- K3a: last-row masked scores ST[t][b] ----------------
__global__ void __launch_bounds__(256) k3a_scores(const float* __restrict__ OUTT, float* __restrict__ ST) {
  int wid = RFL((int)(threadIdx.x >> 6));
  int b = threadIdx.x & 63;
  int t = blockIdx.x * 4 + wid;
  float acc = 0.f;
  for (int dd = 0; dd < 2; ++dd) {
    size_t bt = (size_t)(dd * 512 + t)   * 512;
    size_t bl = (size_t)(dd * 512 + 511) * 512;
    for (int jj = 0; jj < 512; ++jj)
      acc = fmaf(OUTT[(bt + jj) * 64 + b], OUTT[(bl + jj) * 64 + b], acc);
  }
  float sc = acc * (1.0f / 32.0f);
  ST[t * 64 + b] = (sc > 0.1f) ? sc : -1000000.0f;
}

// ---------------- K3b: softmax over t per batch ----------------
__global__ void __launch_bounds__(64) k3b_softmax(const float* __restrict__ ST, float* __restrict__ WT) {
  int b = threadIdx.x;
  float mx = -3.0e38f;
  for (int t = 0; t < 512; ++t) mx = fmaxf(mx, ST[t * 64 + b]);
  float sum = 0.f;
  for (int t = 0; t < 512; ++t) sum += __expf(ST[t * 64 + b] - mx);
  float inv = 1.0f / sum;
  for (int t = 0; t < 512; ++t) WT[t * 64 + b] = __expf(ST[t * 64 + b] - mx) * inv;
}

// ---------------- K3c: context CTX[d*512+j][b] ----------------
__global__ void __launch_bounds__(256) k3c_ctx(const float* __restrict__ OUTT,
    const float* __restrict__ WT, float* __restrict__ CTX) {
  int bq = blockIdx.x;
  int d = bq >> 7, j0 = (bq & 127) * 4;
  int wid = RFL((int)(threadIdx.x >> 6));
  int b = threadIdx.x & 63;
  int j = j0 + wid;
  float acc = 0.f;
  for (int t = 0; t < 512; ++t)
    acc = fmaf(WT[t * 64 + b], OUTT[((size_t)(d * 512 + t) * 512 + j) * 64 + b], acc);
  CTX[(size_t)(d * 512 + j) * 64 + b] = acc;
}

// ---------------- K3d-pre: transpose W_out[256][1024] -> WoT[1024][256] ----------------
__global__ void __launch_bounds__(256) k3dpre(const float* __restrict__ Wout, float* __restrict__ WoT) {
  int o = threadIdx.x;
  int k0 = blockIdx.x * 64;
  for (int k = k0; k < k0 + 64; ++k)
    WoT[k * 256 + o] = Wout[(size_t)o * 1024 + k];
}

// ---------------- K3d: y[b][o] = ctx[b] . WoT[:,o] + b_out[o] ----------------
__global__ void __launch_bounds__(256) k3d_y(const float* __restrict__ CTX,
    const float* __restrict__ WoT, const float* __restrict__ bout, float* __restrict__ y) {
  __shared__ float lc[1024];
  int b = blockIdx.x, o = threadIdx.x;
  for (int k = threadIdx.x; k < 1024; k += 256) lc[k] = CTX[(size_t)k * 64 + b];
  __syncthreads();
  float acc = bout[o];
  for (int k = 0; k < 1024; ++k) acc = fmaf(lc[k], WoT[k * 256 + o], acc);
  y[b * 256 + o] = acc;
}

extern "C" void kernel_launch(void* const* d_in, const int* in_sizes, int n_in,
                              void* d_out, int out_size, void* d_ws, size_t ws_size,
                              hipStream_t stream) {
  (void)in_sizes; (void)n_in; (void)out_size; (void)ws_size;
  const float* inputs = (const float*)d_in[0];
  const float* Wih_f = (const float*)d_in[1];
  const float* Whh_f = (const float*)d_in[2];
  const float* bih_f = (const float*)d_in[3];
  const float* bhh_f = (const float*)d_in[4];
  const float* Wih_b = (const float*)d_in[5];
  const float* Whh_b = (const float*)d_in[6];
  const float* bih_b = (const float*)d_in[7];
  const float* bhh_b = (const float*)d_in[8];
  const float* Wout  = (const float*)d_in[9];
  const float* bout  = (const float*)d_in[10];
  float* y = (float*)d_out;

  float* ws = (float*)d_ws;
  size_t off = 0;
  float* XGa = ws + off; off += (size_t)2 * 32 * 2048 * 64;                    // 32 MB
  float* XGb = ws + off; off += (size_t)2 * 32 * 2048 * 64;                    // 32 MB
  float* OUTT= ws + off; off += (size_t)2 * 512 * 512 * 64;                    // 128 MB
  ushort* HTB = (ushort*)(ws + off); off += (size_t)2 * 2 * 64 * 512;          // 512 KB
  float* Cws = ws + off; off += (size_t)2 * 512 * 64;
  float* ST  = ws + off; off += (size_t)512 * 64;
  float* WT  = ws + off; off += (size_t)512 * 64;
  float* CTX = ws + off; off += (size_t)2 * 512 * 64;
  float* WoT = ws + off; off += (size_t)1024 * 256;
  ushort* WBS = (ushort*)(ws + off); off += (size_t)4 * 2048 * 1024 / 2;       // 16 MB
  unsigned int* Bar = (unsigned int*)(ws + off); off += 1024;                   // 2x32 slots x 16

  hipMemsetAsync(HTB, 0, (size_t)4 * 65536 * sizeof(ushort), stream);
  hipMemsetAsync(Cws, 0, (size_t)2 * 512 * 64 * sizeof(float), stream);
  hipMemsetAsync(Bar, 0, 4096, stream);

  const int ldsK = 8 * 4 * 64 * 20 * 4;   // 163,840 B = 160 KB exactly
  hipFuncSetAttribute(reinterpret_cast<const void*>(k2_fused),
                      hipFuncAttributeMaxDynamicSharedMemorySize, ldsK);
  hipFuncSetAttribute(reinterpret_cast<const void*>(k1_pro),
                      hipFuncAttributeMaxDynamicSharedMemorySize, ldsK);

  kw_split2<<<4096, 256, 0, stream>>>(Whh_f, Whh_b, Wih_f, Wih_b, WBS);
  k1_pro<<<256, 512, ldsK, stream>>>(WBS, inputs, bih_f, bhh_f, bih_b, bhh_b, XGa);

  for (int c = 0; c < 16; ++c) {
    int c0 = c * 32;
    float* xg_r = (c & 1) ? XGb : XGa;
    float* xg_w = (c & 1) ? XGa : XGb;
    void* args[] = { (void*)&WBS, (void*)&inputs, (void*)&xg_r, (void*)&xg_w,
                     (void*)&HTB, (void*)&OUTT, (void*)&Cws, (void*)&Bar,
                     (void*)&bih_f, (void*)&bhh_f, (void*)&bih_b, (void*)&bhh_b,
                     (void*)&c0 };
    hipLaunchCooperativeKernel(reinterpret_cast<void*>(k2_fused),
                               dim3(256), dim3(512), args, ldsK, stream);
  }

  k3a_scores<<<128, 256, 0, stream>>>(OUTT, ST);
  k3b_softmax<<<1, 64, 0, stream>>>(ST, WT);
  k3c_ctx<<<256, 256, 0, stream>>>(OUTT, WT, CTX);
  k3dpre<<<16, 256, 0, stream>>>(Wout, WoT);
  k3d_y<<<64, 256, 0, stream>>>(CTX, WoT, bout, y);
}